// Round 3
// baseline (1046.479 us; speedup 1.0000x reference)
//
#include <hip/hip_runtime.h>
#include <hip/hip_bf16.h>

// PAM (position attention): B=8, C=512, mid=64, N=64*64=4096.
// Round 3: k_attn -> 8-wave blocks, register-double-buffered V prefetch
// (loads issued a phase/iteration ahead, consumed as pure reg MFMA),
// setprio around PV. Numerics identical (hi/lo QK split, bf16 P/V).

#define BB 8
#define CC 512
#define MM 64
#define NN 4096

typedef __attribute__((ext_vector_type(8))) short bf16x8;
typedef __attribute__((ext_vector_type(4))) float f32x4;

__device__ __forceinline__ unsigned short f2bf(float f) {
  union { float f; unsigned u; } v; v.f = f;
  unsigned r = v.u + 0x7fffu + ((v.u >> 16) & 1u);  // RNE
  return (unsigned short)(r >> 16);
}
__device__ __forceinline__ float bf2f(unsigned short h) {
  union { unsigned u; float f; } v; v.u = ((unsigned)h) << 16;
  return v.f;
}

// ---------------- kernel 1: x [B][C][N] f32 -> xT [B][N][C] bf16 ----------------
__global__ __launch_bounds__(256) void k_transpose(const float* __restrict__ x,
                                                   unsigned short* __restrict__ xT) {
  __shared__ float tile[64][65];
  const int b = blockIdx.z, c0 = blockIdx.y * 64, n0 = blockIdx.x * 64;
  const int t = threadIdx.x;
  {
    const int nl = t & 63, cl0 = t >> 6;
    const float* xp = x + ((size_t)b * CC + c0) * NN + n0;
#pragma unroll
    for (int r = 0; r < 16; r++) {
      const int cl = cl0 + r * 4;
      tile[cl][nl] = xp[(size_t)cl * NN + nl];
    }
  }
  __syncthreads();
  {
    const int cl = t & 63, nl0 = t >> 6;
    unsigned short* xtp = xT + ((size_t)b * NN + n0) * CC + c0;
#pragma unroll
    for (int r = 0; r < 16; r++) {
      const int nl = nl0 + r * 4;
      xtp[(size_t)nl * CC + cl] = f2bf(tile[cl][nl]);
    }
  }
}

// ------------- kernel 2: exact fp32 Q/K projection + hi/lo bf16 split -------------
__global__ __launch_bounds__(256) void k_qkproj(
    const float* __restrict__ x, const float* __restrict__ wq, const float* __restrict__ bq,
    const float* __restrict__ wk, const float* __restrict__ bk,
    unsigned short* __restrict__ qhi, unsigned short* __restrict__ qlo,
    unsigned short* __restrict__ khi, unsigned short* __restrict__ klo) {
  __shared__ float xs[64][68];
  __shared__ float wqs[64][65];
  __shared__ float wks[64][65];
  const int b = blockIdx.y, n0 = blockIdx.x * 64;
  const int t = threadIdx.x;
  const int m4 = (t & 15) * 4, n4 = (t >> 4) * 4;
  const int cl = t & 63, r0 = t >> 6;
  float qa[4][4] = {}, ka[4][4] = {};
  for (int c0 = 0; c0 < CC; c0 += 64) {
    __syncthreads();
#pragma unroll
    for (int r = 0; r < 16; r++) {
      const int row = r0 + r * 4;
      xs[row][cl] = x[((size_t)b * CC + c0 + row) * NN + n0 + cl];
      wqs[row][cl] = wq[(size_t)row * CC + c0 + cl];
      wks[row][cl] = wk[(size_t)row * CC + c0 + cl];
    }
    __syncthreads();
#pragma unroll 8
    for (int cc = 0; cc < 64; cc++) {
      const f32x4 xv = *reinterpret_cast<const f32x4*>(&xs[cc][n4]);
#pragma unroll
      for (int mi = 0; mi < 4; mi++) {
        const float wqv = wqs[m4 + mi][cc];
        const float wkv = wks[m4 + mi][cc];
#pragma unroll
        for (int ni = 0; ni < 4; ni++) {
          qa[mi][ni] += wqv * xv[ni];
          ka[mi][ni] += wkv * xv[ni];
        }
      }
    }
  }
#pragma unroll
  for (int ni = 0; ni < 4; ni++) {
    const int n = n0 + n4 + ni;
    const size_t base = ((size_t)b * NN + n) * MM + m4;
    unsigned short qh[4], qlo_[4], kh[4], klo_[4];
#pragma unroll
    for (int mi = 0; mi < 4; mi++) {
      const float qv = qa[mi][ni] + bq[m4 + mi];
      const unsigned short h = f2bf(qv);
      qh[mi] = h; qlo_[mi] = f2bf(qv - bf2f(h));
      const float kv = ka[mi][ni] + bk[m4 + mi];
      const unsigned short h2 = f2bf(kv);
      kh[mi] = h2; klo_[mi] = f2bf(kv - bf2f(h2));
    }
    *reinterpret_cast<ushort4*>(qhi + base) = make_ushort4(qh[0], qh[1], qh[2], qh[3]);
    *reinterpret_cast<ushort4*>(qlo + base) = make_ushort4(qlo_[0], qlo_[1], qlo_[2], qlo_[3]);
    *reinterpret_cast<ushort4*>(khi + base) = make_ushort4(kh[0], kh[1], kh[2], kh[3]);
    *reinterpret_cast<ushort4*>(klo + base) = make_ushort4(klo_[0], klo_[1], klo_[2], klo_[3]);
  }
}

// ---------------- kernel 3: V projection (bf16 MFMA) -> v [B][C][N] bf16 ----------------
__global__ __launch_bounds__(256) void k_vproj(
    const unsigned short* __restrict__ xT, const float* __restrict__ wv,
    const float* __restrict__ bv, unsigned short* __restrict__ vbf) {
  const int b = blockIdx.z, c0 = blockIdx.y * 64, n0 = blockIdx.x * 128;
  const int t = threadIdx.x, w = t >> 6, l = t & 63, lr = l & 15, g = l >> 4;
  const int nbase = n0 + w * 32;
  f32x4 acc[4][2] = {};
  for (int ks = 0; ks < 16; ks++) {
    const int kk = ks * 32 + g * 8;
    bf16x8 bfr[2];
#pragma unroll
    for (int nf = 0; nf < 2; nf++) {
      const int n = nbase + nf * 16 + lr;
      bfr[nf] = *reinterpret_cast<const bf16x8*>(xT + ((size_t)b * NN + n) * CC + kk);
    }
#pragma unroll
    for (int cf = 0; cf < 4; cf++) {
      const int c = c0 + cf * 16 + lr;
      const float* wp = wv + (size_t)c * CC + kk;
      const f32x4 w0 = *reinterpret_cast<const f32x4*>(wp);
      const f32x4 w1 = *reinterpret_cast<const f32x4*>(wp + 4);
      bf16x8 af;
      af[0] = (short)f2bf(w0[0]); af[1] = (short)f2bf(w0[1]);
      af[2] = (short)f2bf(w0[2]); af[3] = (short)f2bf(w0[3]);
      af[4] = (short)f2bf(w1[0]); af[5] = (short)f2bf(w1[1]);
      af[6] = (short)f2bf(w1[2]); af[7] = (short)f2bf(w1[3]);
      acc[cf][0] = __builtin_amdgcn_mfma_f32_16x16x32_bf16(af, bfr[0], acc[cf][0], 0, 0, 0);
      acc[cf][1] = __builtin_amdgcn_mfma_f32_16x16x32_bf16(af, bfr[1], acc[cf][1], 0, 0, 0);
    }
  }
#pragma unroll
  for (int cf = 0; cf < 4; cf++) {
#pragma unroll
    for (int r = 0; r < 4; r++) {
      const int c = c0 + cf * 16 + g * 4 + r;
      const float bvv = bv[c];
#pragma unroll
      for (int nf = 0; nf < 2; nf++) {
        const int n = nbase + nf * 16 + lr;
        vbf[((size_t)b * CC + c) * NN + n] = f2bf(acc[cf][nf][r] + bvv);
      }
    }
  }
}

// ---------------- kernel 4: flash attention + residual ----------------
// 8 waves (512 thr), I_TILE=32, JT=128.
// QK: wave w computes i-frag (w&1), j-frag pair (w>>1) -> S^T in LDS.
// Softmax: wave w owns rows [4w,4w+4); 16-lane group per row, 8 entries/lane.
// PV: wave w owns c-strip [64w, 64w+64); V reg-double-buffered one phase ahead:
//   vA(jb) loaded at end of prev PV (covered by QK+softmax), vB(jb) issued
//   during softmax (covered by barrier+rescale+half-A MFMAs).
__global__ __launch_bounds__(512, 4) void k_attn(
    const unsigned short* __restrict__ qhi, const unsigned short* __restrict__ qlo,
    const unsigned short* __restrict__ khi, const unsigned short* __restrict__ klo,
    const unsigned short* __restrict__ vbf, const float* __restrict__ x,
    const float* __restrict__ gamma, float* __restrict__ out) {
  __shared__ float S_lds[32][132];
  __shared__ unsigned short P_lds[32][136];
  __shared__ float scale_lds[32];
  __shared__ float sfin_lds[32];
  const int b = blockIdx.x & 7;  // batch-pinned XCD swizzle
  const int i0 = (blockIdx.x >> 3) * 32;
  const int t = threadIdx.x, w = t >> 6, l = t & 63, lr = l & 15, g = l >> 4;
  const int if_ = w & 1;       // QK: i-frag
  const int jfp = w >> 1;      // QK: j-frag pair (j-frags 2*jfp, 2*jfp+1)
  const int srow = w * 4 + g;  // softmax row ownership
  const int wc = w * 64;       // PV channel strip base

  // hoisted Q fragments for this wave's i-frag
  bf16x8 qhF[2], qlF[2];
  {
    const int i = i0 + if_ * 16 + lr;
#pragma unroll
    for (int ks = 0; ks < 2; ks++) {
      const size_t off = ((size_t)b * NN + i) * MM + ks * 32 + g * 8;
      qhF[ks] = *reinterpret_cast<const bf16x8*>(qhi + off);
      qlF[ks] = *reinterpret_cast<const bf16x8*>(qlo + off);
    }
  }

  // K element-offset base: j = jb + jfp*32 + jj*16 + lr
  const size_t kbase = ((size_t)b * NN + jfp * 32 + lr) * MM + g * 8;
  // V row base for c = wc + cf*16 + lr (cf steps by 16*NN elements)
  const unsigned short* pv = vbf + ((size_t)b * CC + wc + lr) * NN + g * 8;

  f32x4 acc[4][2];
#pragma unroll
  for (int cf = 0; cf < 4; cf++) {
    acc[cf][0] = f32x4{0.f, 0.f, 0.f, 0.f};
    acc[cf][1] = f32x4{0.f, 0.f, 0.f, 0.f};
  }
  float m_run = -1e30f, s_run = 0.f;

  // V register double-buffers: vA = ks{0,1}, vB = ks{2,3} of current jb
  bf16x8 vA[2][4], vB[2][4];
#pragma unroll
  for (int ks = 0; ks < 2; ks++)
#pragma unroll
    for (int cf = 0; cf < 4; cf++)
      vA[ks][cf] = *reinterpret_cast<const bf16x8*>(pv + (size_t)cf * (16 * NN) + ks * 32);

  for (int jb = 0; jb < NN; jb += 128) {
    // ---- QK: S^T fragments (3-term hi/lo)
#pragma unroll
    for (int jj = 0; jj < 2; jj++) {
      f32x4 sa = f32x4{0.f, 0.f, 0.f, 0.f};
#pragma unroll
      for (int ks = 0; ks < 2; ks++) {
        const size_t off = kbase + (size_t)(jb + jj * 16) * MM + ks * 32;
        const bf16x8 kh = *reinterpret_cast<const bf16x8*>(khi + off);
        const bf16x8 kl = *reinterpret_cast<const bf16x8*>(klo + off);
        sa = __builtin_amdgcn_mfma_f32_16x16x32_bf16(kh, qhF[ks], sa, 0, 0, 0);
        sa = __builtin_amdgcn_mfma_f32_16x16x32_bf16(kh, qlF[ks], sa, 0, 0, 0);
        sa = __builtin_amdgcn_mfma_f32_16x16x32_bf16(kl, qhF[ks], sa, 0, 0, 0);
      }
      *reinterpret_cast<f32x4*>(&S_lds[if_ * 16 + lr][(jfp * 2 + jj) * 16 + g * 4]) = sa;
    }
    __syncthreads();

    // ---- softmax: row srow, lane handles 8 entries [lr*8, lr*8+8)
    {
      const f32x4 s0 = *reinterpret_cast<const f32x4*>(&S_lds[srow][lr * 8]);
      const f32x4 s1 = *reinterpret_cast<const f32x4*>(&S_lds[srow][lr * 8 + 4]);
      float tm = fmaxf(fmaxf(fmaxf(s0[0], s0[1]), fmaxf(s0[2], s0[3])),
                       fmaxf(fmaxf(s1[0], s1[1]), fmaxf(s1[2], s1[3])));
      tm = fmaxf(tm, __shfl_xor(tm, 1));
      tm = fmaxf(tm, __shfl_xor(tm, 2));
      tm = fmaxf(tm, __shfl_xor(tm, 4));
      tm = fmaxf(tm, __shfl_xor(tm, 8));
      const float mn = fmaxf(m_run, tm);
      const float sc = __expf(m_run - mn);
      m_run = mn;
      float p[8];
      p[0] = __expf(s0[0] - mn); p[1] = __expf(s0[1] - mn);
      p[2] = __expf(s0[2] - mn); p[3] = __expf(s0[3] - mn);
      p[4] = __expf(s1[0] - mn); p[5] = __expf(s1[1] - mn);
      p[6] = __expf(s1[2] - mn); p[7] = __expf(s1[3] - mn);
      float ps = ((p[0] + p[1]) + (p[2] + p[3])) + ((p[4] + p[5]) + (p[6] + p[7]));
      ps += __shfl_xor(ps, 1);
      ps += __shfl_xor(ps, 2);
      ps += __shfl_xor(ps, 4);
      ps += __shfl_xor(ps, 8);
      s_run = s_run * sc + ps;
      bf16x8 pp;
#pragma unroll
      for (int e = 0; e < 8; e++) pp[e] = (short)f2bf(p[e]);
      *reinterpret_cast<bf16x8*>(&P_lds[srow][lr * 8]) = pp;
      if (lr == 0) scale_lds[srow] = sc;
    }
    // issue vB (ks 2,3) — consumed after half-A MFMAs
#pragma unroll
    for (int ks = 0; ks < 2; ks++)
#pragma unroll
      for (int cf = 0; cf < 4; cf++)
        vB[ks][cf] = *reinterpret_cast<const bf16x8*>(
            pv + (size_t)cf * (16 * NN) + jb + (ks + 2) * 32);
    __syncthreads();

    // ---- PV
    {
      const float sc0 = scale_lds[lr], sc1 = scale_lds[16 + lr];
      if (__any((sc0 != 1.f) || (sc1 != 1.f))) {
#pragma unroll
        for (int cf = 0; cf < 4; cf++) {
          acc[cf][0] *= sc0;
          acc[cf][1] *= sc1;
        }
      }
    }
    __builtin_amdgcn_s_setprio(1);
#pragma unroll
    for (int ks = 0; ks < 2; ks++) {
      const bf16x8 pf0 = *reinterpret_cast<const bf16x8*>(&P_lds[lr][ks * 32 + g * 8]);
      const bf16x8 pf1 = *reinterpret_cast<const bf16x8*>(&P_lds[16 + lr][ks * 32 + g * 8]);
#pragma unroll
      for (int cf = 0; cf < 4; cf++) {
        acc[cf][0] = __builtin_amdgcn_mfma_f32_16x16x32_bf16(vA[ks][cf], pf0, acc[cf][0], 0, 0, 0);
        acc[cf][1] = __builtin_amdgcn_mfma_f32_16x16x32_bf16(vA[ks][cf], pf1, acc[cf][1], 0, 0, 0);
      }
    }
#pragma unroll
    for (int ks = 0; ks < 2; ks++) {
      const bf16x8 pf0 = *reinterpret_cast<const bf16x8*>(&P_lds[lr][(ks + 2) * 32 + g * 8]);
      const bf16x8 pf1 = *reinterpret_cast<const bf16x8*>(&P_lds[16 + lr][(ks + 2) * 32 + g * 8]);
#pragma unroll
      for (int cf = 0; cf < 4; cf++) {
        acc[cf][0] = __builtin_amdgcn_mfma_f32_16x16x32_bf16(vB[ks][cf], pf0, acc[cf][0], 0, 0, 0);
        acc[cf][1] = __builtin_amdgcn_mfma_f32_16x16x32_bf16(vB[ks][cf], pf1, acc[cf][1], 0, 0, 0);
      }
    }
    __builtin_amdgcn_s_setprio(0);
    // reload vA for next jb — consumed after next QK+softmax (huge latency window)
    const int jn = (jb + 128) & (NN - 1);
#pragma unroll
    for (int ks = 0; ks < 2; ks++)
#pragma unroll
      for (int cf = 0; cf < 4; cf++)
        vA[ks][cf] = *reinterpret_cast<const bf16x8*>(
            pv + (size_t)cf * (16 * NN) + jn + ks * 32);
  }

  // ---- epilogue: out = gamma * O/s + x
  if (lr == 0) sfin_lds[srow] = s_run;
  __syncthreads();
  const float gm = gamma[0];
  const float inv0 = gm / sfin_lds[lr], inv1 = gm / sfin_lds[16 + lr];
#pragma unroll
  for (int cf = 0; cf < 4; cf++) {
#pragma unroll
    for (int r = 0; r < 4; r++) {
      const int c = wc + cf * 16 + g * 4 + r;
      const size_t rowo = ((size_t)b * CC + c) * NN;
      out[rowo + i0 + lr] = acc[cf][0][r] * inv0 + x[rowo + i0 + lr];
      out[rowo + i0 + 16 + lr] = acc[cf][1][r] * inv1 + x[rowo + i0 + 16 + lr];
    }
  }
}

extern "C" void kernel_launch(void* const* d_in, const int* in_sizes, int n_in,
                              void* d_out, int out_size, void* d_ws, size_t ws_size,
                              hipStream_t stream) {
  const float* x = (const float*)d_in[0];
  const float* wq = (const float*)d_in[1];
  const float* bq = (const float*)d_in[2];
  const float* wk = (const float*)d_in[3];
  const float* bk = (const float*)d_in[4];
  const float* wv = (const float*)d_in[5];
  const float* bv = (const float*)d_in[6];
  const float* gamma = (const float*)d_in[7];
  float* out = (float*)d_out;

  char* ws = (char*)d_ws;
  unsigned short* xT = (unsigned short*)(ws);               // 32 MB  [B][N][C] bf16
  unsigned short* vbf = (unsigned short*)(ws + 33554432);   // 32 MB  [B][C][N] bf16
  unsigned short* qhi = (unsigned short*)(ws + 67108864);   // 4 MB   [B][N][64] bf16
  unsigned short* qlo = (unsigned short*)(ws + 71303168);   // 4 MB
  unsigned short* khi = (unsigned short*)(ws + 75497472);   // 4 MB
  unsigned short* klo = (unsigned short*)(ws + 79691776);   // 4 MB

  k_transpose<<<dim3(64, 8, 8), 256, 0, stream>>>(x, xT);
  k_qkproj<<<dim3(64, 8), 256, 0, stream>>>(x, wq, bq, wk, bk, qhi, qlo, khi, klo);
  k_vproj<<<dim3(32, 8, 8), 256, 0, stream>>>(xT, wv, bv, vbf);
  k_attn<<<dim3(1024), 512, 0, stream>>>(qhi, qlo, khi, klo, vbf, x, gamma, out);
}

// Round 4
// 935.951 us; speedup vs baseline: 1.1181x; 1.1181x over previous
//
#include <hip/hip_runtime.h>
#include <hip/hip_bf16.h>

// PAM (position attention): B=8, C=512, mid=64, N=64*64=4096.
// Round 4: k_attn rewritten m214-style:
//  - softmax via a-priori row bound mhat_i = ||q_i||*max||k|| - 44 (shift-
//    invariance: no online max, no rescale, no cross-lane reductions in loop)
//  - swapped QK (A=K,B=Q): S^T lane-local in regs -> exp -> tiny dbuf P_lds
//  - ONE barrier/iter; K,V register-prefetched a phase ahead; setprio on PV.

#define BB 8
#define CC 512
#define MM 64
#define NN 4096

typedef __attribute__((ext_vector_type(8))) short bf16x8;
typedef __attribute__((ext_vector_type(4))) float f32x4;

__device__ unsigned g_kmax[BB];  // per-batch max ||k||^2 (as uint-ordered f32)

__device__ __forceinline__ unsigned short f2bf(float f) {
  union { float f; unsigned u; } v; v.f = f;
  unsigned r = v.u + 0x7fffu + ((v.u >> 16) & 1u);  // RNE
  return (unsigned short)(r >> 16);
}
__device__ __forceinline__ float bf2f(unsigned short h) {
  union { unsigned u; float f; } v; v.u = ((unsigned)h) << 16;
  return v.f;
}

__global__ void k_init() {
  if (threadIdx.x < BB) g_kmax[threadIdx.x] = 0u;
}

// ---------------- kernel 1: x [B][C][N] f32 -> xT [B][N][C] bf16 ----------------
__global__ __launch_bounds__(256) void k_transpose(const float* __restrict__ x,
                                                   unsigned short* __restrict__ xT) {
  __shared__ float tile[64][65];
  const int b = blockIdx.z, c0 = blockIdx.y * 64, n0 = blockIdx.x * 64;
  const int t = threadIdx.x;
  {
    const int nl = t & 63, cl0 = t >> 6;
    const float* xp = x + ((size_t)b * CC + c0) * NN + n0;
#pragma unroll
    for (int r = 0; r < 16; r++) {
      const int cl = cl0 + r * 4;
      tile[cl][nl] = xp[(size_t)cl * NN + nl];
    }
  }
  __syncthreads();
  {
    const int cl = t & 63, nl0 = t >> 6;
    unsigned short* xtp = xT + ((size_t)b * NN + n0) * CC + c0;
#pragma unroll
    for (int r = 0; r < 16; r++) {
      const int nl = nl0 + r * 4;
      xtp[(size_t)nl * CC + cl] = f2bf(tile[cl][nl]);
    }
  }
}

// ------------- kernel 2: exact fp32 Q/K projection + hi/lo bf16 split -------------
// Also: per-batch max ||k_n||^2 via wave-reduce + atomicMax into g_kmax.
__global__ __launch_bounds__(256) void k_qkproj(
    const float* __restrict__ x, const float* __restrict__ wq, const float* __restrict__ bq,
    const float* __restrict__ wk, const float* __restrict__ bk,
    unsigned short* __restrict__ qhi, unsigned short* __restrict__ qlo,
    unsigned short* __restrict__ khi, unsigned short* __restrict__ klo) {
  __shared__ float xs[64][68];
  __shared__ float wqs[64][65];
  __shared__ float wks[64][65];
  const int b = blockIdx.y, n0 = blockIdx.x * 64;
  const int t = threadIdx.x;
  const int m4 = (t & 15) * 4, n4 = (t >> 4) * 4;
  const int cl = t & 63, r0 = t >> 6;
  float qa[4][4] = {}, ka[4][4] = {};
  for (int c0 = 0; c0 < CC; c0 += 64) {
    __syncthreads();
#pragma unroll
    for (int r = 0; r < 16; r++) {
      const int row = r0 + r * 4;
      xs[row][cl] = x[((size_t)b * CC + c0 + row) * NN + n0 + cl];
      wqs[row][cl] = wq[(size_t)row * CC + c0 + cl];
      wks[row][cl] = wk[(size_t)row * CC + c0 + cl];
    }
    __syncthreads();
#pragma unroll 8
    for (int cc = 0; cc < 64; cc++) {
      const f32x4 xv = *reinterpret_cast<const f32x4*>(&xs[cc][n4]);
#pragma unroll
      for (int mi = 0; mi < 4; mi++) {
        const float wqv = wqs[m4 + mi][cc];
        const float wkv = wks[m4 + mi][cc];
#pragma unroll
        for (int ni = 0; ni < 4; ni++) {
          qa[mi][ni] += wqv * xv[ni];
          ka[mi][ni] += wkv * xv[ni];
        }
      }
    }
  }
  float kss[4] = {0.f, 0.f, 0.f, 0.f};
#pragma unroll
  for (int ni = 0; ni < 4; ni++) {
    const int n = n0 + n4 + ni;
    const size_t base = ((size_t)b * NN + n) * MM + m4;
    unsigned short qh[4], qlo_[4], kh[4], klo_[4];
#pragma unroll
    for (int mi = 0; mi < 4; mi++) {
      const float qv = qa[mi][ni] + bq[m4 + mi];
      const unsigned short h = f2bf(qv);
      qh[mi] = h; qlo_[mi] = f2bf(qv - bf2f(h));
      const float kv = ka[mi][ni] + bk[m4 + mi];
      const unsigned short h2 = f2bf(kv);
      kh[mi] = h2; klo_[mi] = f2bf(kv - bf2f(h2));
      kss[ni] += kv * kv;
    }
    *reinterpret_cast<ushort4*>(qhi + base) = make_ushort4(qh[0], qh[1], qh[2], qh[3]);
    *reinterpret_cast<ushort4*>(qlo + base) = make_ushort4(qlo_[0], qlo_[1], qlo_[2], qlo_[3]);
    *reinterpret_cast<ushort4*>(khi + base) = make_ushort4(kh[0], kh[1], kh[2], kh[3]);
    *reinterpret_cast<ushort4*>(klo + base) = make_ushort4(klo_[0], klo_[1], klo_[2], klo_[3]);
  }
  // reduce ||k_n||^2 over the 16-lane m-groups, then per-batch atomic max
#pragma unroll
  for (int ni = 0; ni < 4; ni++) {
    kss[ni] += __shfl_xor(kss[ni], 1);
    kss[ni] += __shfl_xor(kss[ni], 2);
    kss[ni] += __shfl_xor(kss[ni], 4);
    kss[ni] += __shfl_xor(kss[ni], 8);
  }
  if ((t & 15) == 0) {
    float mx = fmaxf(fmaxf(kss[0], kss[1]), fmaxf(kss[2], kss[3]));
    atomicMax(&g_kmax[b], __float_as_uint(mx));
  }
}

// ---------------- kernel 3: V projection (bf16 MFMA) -> v [B][C][N] bf16 ----------------
__global__ __launch_bounds__(256) void k_vproj(
    const unsigned short* __restrict__ xT, const float* __restrict__ wv,
    const float* __restrict__ bv, unsigned short* __restrict__ vbf) {
  const int b = blockIdx.z, c0 = blockIdx.y * 64, n0 = blockIdx.x * 128;
  const int t = threadIdx.x, w = t >> 6, l = t & 63, lr = l & 15, g = l >> 4;
  const int nbase = n0 + w * 32;
  f32x4 acc[4][2] = {};
  for (int ks = 0; ks < 16; ks++) {
    const int kk = ks * 32 + g * 8;
    bf16x8 bfr[2];
#pragma unroll
    for (int nf = 0; nf < 2; nf++) {
      const int n = nbase + nf * 16 + lr;
      bfr[nf] = *reinterpret_cast<const bf16x8*>(xT + ((size_t)b * NN + n) * CC + kk);
    }
#pragma unroll
    for (int cf = 0; cf < 4; cf++) {
      const int c = c0 + cf * 16 + lr;
      const float* wp = wv + (size_t)c * CC + kk;
      const f32x4 w0 = *reinterpret_cast<const f32x4*>(wp);
      const f32x4 w1 = *reinterpret_cast<const f32x4*>(wp + 4);
      bf16x8 af;
      af[0] = (short)f2bf(w0[0]); af[1] = (short)f2bf(w0[1]);
      af[2] = (short)f2bf(w0[2]); af[3] = (short)f2bf(w0[3]);
      af[4] = (short)f2bf(w1[0]); af[5] = (short)f2bf(w1[1]);
      af[6] = (short)f2bf(w1[2]); af[7] = (short)f2bf(w1[3]);
      acc[cf][0] = __builtin_amdgcn_mfma_f32_16x16x32_bf16(af, bfr[0], acc[cf][0], 0, 0, 0);
      acc[cf][1] = __builtin_amdgcn_mfma_f32_16x16x32_bf16(af, bfr[1], acc[cf][1], 0, 0, 0);
    }
  }
#pragma unroll
  for (int cf = 0; cf < 4; cf++) {
#pragma unroll
    for (int r = 0; r < 4; r++) {
      const int c = c0 + cf * 16 + g * 4 + r;
      const float bvv = bv[c];
#pragma unroll
      for (int nf = 0; nf < 2; nf++) {
        const int n = nbase + nf * 16 + lr;
        vbf[((size_t)b * CC + c) * NN + n] = f2bf(acc[cf][nf][r] + bvv);
      }
    }
  }
}

// ---------------- kernel 4: attention + residual (bound-softmax) ----------------
// 4 waves (256 thr), I_TILE=32, JT=64, 64 iters, ONE barrier per iter.
// QK swapped (A=K, B=Q): wave w -> i-frag (w&1), j-frags (w>>1)*2+{0,1}.
//   D is lane-local in i: exp(s - mhat_i) straight from regs, cvt bf16,
//   b64-write into double-buffered P_lds[buf][i][j].
// PV: wave w owns c-strip [128w,128w+128); V (16 frags) + K (8 frags)
//   register-prefetched one phase ahead.
__global__ __launch_bounds__(256, 2) void k_attn(
    const unsigned short* __restrict__ qhi, const unsigned short* __restrict__ qlo,
    const unsigned short* __restrict__ khi, const unsigned short* __restrict__ klo,
    const unsigned short* __restrict__ vbf, const float* __restrict__ x,
    const float* __restrict__ gamma, float* __restrict__ out) {
  __shared__ unsigned short P_lds[2][32][72];  // [buf][i][j] bf16, 144B rows
  __shared__ float l_red[4][32];
  const int b = blockIdx.x & 7;  // batch-pinned XCD swizzle
  const int i0 = (blockIdx.x >> 3) * 32;
  const int t = threadIdx.x, w = t >> 6, l = t & 63, lr = l & 15, g = l >> 4;
  const int if_ = w & 1;        // QK i-frag
  const int jf0 = (w >> 1) * 2; // QK j-frag pair base
  const int wc = w * 128;       // PV channel strip

  // ---- Q fragments (hi/lo), i = i0 + if_*16 + lr, k = ks*32 + g*8 + e
  bf16x8 qhF[2], qlF[2];
  {
    const int i = i0 + if_ * 16 + lr;
#pragma unroll
    for (int ks = 0; ks < 2; ks++) {
      const size_t off = ((size_t)b * NN + i) * MM + ks * 32 + g * 8;
      qhF[ks] = *reinterpret_cast<const bf16x8*>(qhi + off);
      qlF[ks] = *reinterpret_cast<const bf16x8*>(qlo + off);
    }
  }
  // ---- mhat = ||q_i|| * max||k|| - 44  (Cauchy-Schwarz bound, shift-invariant)
  float mhat;
  {
    float ssq = 0.f;
#pragma unroll
    for (int ks = 0; ks < 2; ks++)
#pragma unroll
      for (int e = 0; e < 8; e++) {
        const float qv = bf2f((unsigned short)qhF[ks][e]) + bf2f((unsigned short)qlF[ks][e]);
        ssq += qv * qv;
      }
    ssq += __shfl_xor(ssq, 16);
    ssq += __shfl_xor(ssq, 32);
    mhat = sqrtf(ssq) * sqrtf(__uint_as_float(g_kmax[b])) - 44.f;
  }

  // K base: j = jb + (jf0+jf)*16 + lr
  const size_t kbase = ((size_t)b * NN + jf0 * 16 + lr) * MM + g * 8;
  // V base: c = wc + cf*16 + lr, col j = jb + ks*32 + g*8
  const unsigned short* pv = vbf + ((size_t)b * CC + wc + lr) * NN + g * 8;

  f32x4 acc[8][2];
#pragma unroll
  for (int cf = 0; cf < 8; cf++) {
    acc[cf][0] = f32x4{0.f, 0.f, 0.f, 0.f};
    acc[cf][1] = f32x4{0.f, 0.f, 0.f, 0.f};
  }
  float lsum = 0.f;

  // prologue prefetch: K(0), V(0)
  bf16x8 kh[2][2], klo_r[2][2];  // [jf][ks]
  bf16x8 vr[2][8];               // [ks][cf]
#pragma unroll
  for (int jf = 0; jf < 2; jf++)
#pragma unroll
    for (int ks = 0; ks < 2; ks++) {
      const size_t off = kbase + (size_t)(jf * 16) * MM + ks * 32;
      kh[jf][ks] = *reinterpret_cast<const bf16x8*>(khi + off);
      klo_r[jf][ks] = *reinterpret_cast<const bf16x8*>(klo + off);
    }
#pragma unroll
  for (int ks = 0; ks < 2; ks++)
#pragma unroll
    for (int cf = 0; cf < 8; cf++)
      vr[ks][cf] = *reinterpret_cast<const bf16x8*>(pv + (size_t)cf * (16 * NN) + ks * 32);

  for (int jb = 0; jb < NN; jb += 64) {
    const int buf = (jb >> 6) & 1;
    const int jn = (jb + 64) & (NN - 1);  // next tile (wraps harmlessly at end)

    // ---- QK (uses prefetched K), exp, P write
#pragma unroll
    for (int jf = 0; jf < 2; jf++) {
      f32x4 sa = f32x4{0.f, 0.f, 0.f, 0.f};
#pragma unroll
      for (int ks = 0; ks < 2; ks++) {
        sa = __builtin_amdgcn_mfma_f32_16x16x32_bf16(kh[jf][ks], qhF[ks], sa, 0, 0, 0);
        sa = __builtin_amdgcn_mfma_f32_16x16x32_bf16(kh[jf][ks], qlF[ks], sa, 0, 0, 0);
        sa = __builtin_amdgcn_mfma_f32_16x16x32_bf16(klo_r[jf][ks], qhF[ks], sa, 0, 0, 0);
      }
      float p0 = __expf(sa[0] - mhat), p1 = __expf(sa[1] - mhat);
      float p2 = __expf(sa[2] - mhat), p3 = __expf(sa[3] - mhat);
      lsum += (p0 + p1) + (p2 + p3);
      ushort4 pq = make_ushort4(f2bf(p0), f2bf(p1), f2bf(p2), f2bf(p3));
      *reinterpret_cast<ushort4*>(&P_lds[buf][if_ * 16 + lr][(jf0 + jf) * 16 + g * 4]) = pq;
    }
    __syncthreads();  // P tile ready (also drains K/V prefetch issued last iter)

    // ---- issue K prefetch for next tile (covered by PV phase)
#pragma unroll
    for (int jf = 0; jf < 2; jf++)
#pragma unroll
      for (int ks = 0; ks < 2; ks++) {
        const size_t off = kbase + (size_t)(jn + jf * 16) * MM + ks * 32;
        kh[jf][ks] = *reinterpret_cast<const bf16x8*>(khi + off);
        klo_r[jf][ks] = *reinterpret_cast<const bf16x8*>(klo + off);
      }

    // ---- PV (V from regs, P from LDS)
    __builtin_amdgcn_s_setprio(1);
#pragma unroll
    for (int ks = 0; ks < 2; ks++) {
      const bf16x8 pf0 = *reinterpret_cast<const bf16x8*>(&P_lds[buf][lr][ks * 32 + g * 8]);
      const bf16x8 pf1 = *reinterpret_cast<const bf16x8*>(&P_lds[buf][16 + lr][ks * 32 + g * 8]);
#pragma unroll
      for (int cf = 0; cf < 8; cf++) {
        acc[cf][0] = __builtin_amdgcn_mfma_f32_16x16x32_bf16(vr[ks][cf], pf0, acc[cf][0], 0, 0, 0);
        acc[cf][1] = __builtin_amdgcn_mfma_f32_16x16x32_bf16(vr[ks][cf], pf1, acc[cf][1], 0, 0, 0);
      }
    }
    __builtin_amdgcn_s_setprio(0);

    // ---- issue V prefetch for next tile (covered by next QK+exp+barrier)
#pragma unroll
    for (int ks = 0; ks < 2; ks++)
#pragma unroll
      for (int cf = 0; cf < 8; cf++)
        vr[ks][cf] = *reinterpret_cast<const bf16x8*>(pv + (size_t)cf * (16 * NN) + jn + ks * 32);
  }

  // ---- final l reduction: over g (shfl) then over wave pairs (LDS)
  lsum += __shfl_xor(lsum, 16);
  lsum += __shfl_xor(lsum, 32);
  if (l < 16) l_red[w][if_ * 16 + lr] = lsum;
  __syncthreads();
  const float gm = gamma[0];
  const float inv0 = gm / (l_red[0][lr] + l_red[2][lr]);
  const float inv1 = gm / (l_red[1][16 + lr] + l_red[3][16 + lr]);

  // ---- epilogue: out = gamma * O / l + x
#pragma unroll
  for (int cf = 0; cf < 8; cf++) {
#pragma unroll
    for (int r = 0; r < 4; r++) {
      const int c = wc + cf * 16 + g * 4 + r;
      const size_t rowo = ((size_t)b * CC + c) * NN;
      out[rowo + i0 + lr] = acc[cf][0][r] * inv0 + x[rowo + i0 + lr];
      out[rowo + i0 + 16 + lr] = acc[cf][1][r] * inv1 + x[rowo + i0 + 16 + lr];
    }
  }
}

extern "C" void kernel_launch(void* const* d_in, const int* in_sizes, int n_in,
                              void* d_out, int out_size, void* d_ws, size_t ws_size,
                              hipStream_t stream) {
  const float* x = (const float*)d_in[0];
  const float* wq = (const float*)d_in[1];
  const float* bq = (const float*)d_in[2];
  const float* wk = (const float*)d_in[3];
  const float* bk = (const float*)d_in[4];
  const float* wv = (const float*)d_in[5];
  const float* bv = (const float*)d_in[6];
  const float* gamma = (const float*)d_in[7];
  float* out = (float*)d_out;

  char* ws = (char*)d_ws;
  unsigned short* xT = (unsigned short*)(ws);               // 32 MB  [B][N][C] bf16
  unsigned short* vbf = (unsigned short*)(ws + 33554432);   // 32 MB  [B][C][N] bf16
  unsigned short* qhi = (unsigned short*)(ws + 67108864);   // 4 MB   [B][N][64] bf16
  unsigned short* qlo = (unsigned short*)(ws + 71303168);   // 4 MB
  unsigned short* khi = (unsigned short*)(ws + 75497472);   // 4 MB
  unsigned short* klo = (unsigned short*)(ws + 79691776);   // 4 MB

  k_init<<<1, 64, 0, stream>>>();
  k_transpose<<<dim3(64, 8, 8), 256, 0, stream>>>(x, xT);
  k_qkproj<<<dim3(64, 8), 256, 0, stream>>>(x, wq, bq, wk, bk, qhi, qlo, khi, klo);
  k_vproj<<<dim3(32, 8, 8), 256, 0, stream>>>(xT, wv, bv, vbf);
  k_attn<<<dim3(1024), 256, 0, stream>>>(qhi, qlo, khi, klo, vbf, x, gamma, out);
}

// Round 5
// 610.065 us; speedup vs baseline: 1.7154x; 1.5342x over previous
//
#include <hip/hip_runtime.h>
#include <hip/hip_bf16.h>

// PAM (position attention): B=8, C=512, mid=64, N=64*64=4096.
// Round 5: k_attn with (1) raw s_barrier + lgkmcnt-only drain so K/V register
// prefetches survive across the per-iter barrier (compiler's __syncthreads
// vmcnt(0) drain was the round-4 serializer), (2) I_TILE=64 (halved K/V cache
// traffic), (3) single-term fp16 QK (1 MFMA per frag instead of 3; logit err
// ~5e-3 << 0.115 threshold). P/V stay bf16; bound-softmax (Cauchy-Schwarz
// mhat) unchanged from round 4.

#define BB 8
#define CC 512
#define MM 64
#define NN 4096

typedef __attribute__((ext_vector_type(8))) short bf16x8;
typedef __attribute__((ext_vector_type(8))) _Float16 f16x8;
typedef __attribute__((ext_vector_type(4))) float f32x4;

__device__ unsigned g_kmax[BB];  // per-batch max ||k||^2 (uint-ordered f32)

__device__ __forceinline__ unsigned short f2bf(float f) {
  union { float f; unsigned u; } v; v.f = f;
  unsigned r = v.u + 0x7fffu + ((v.u >> 16) & 1u);  // RNE
  return (unsigned short)(r >> 16);
}
__device__ __forceinline__ unsigned short f2h(float f) {
  _Float16 h = (_Float16)f;
  union { _Float16 h; unsigned short u; } v; v.h = h;
  return v.u;
}

__global__ void k_init() {
  if (threadIdx.x < BB) g_kmax[threadIdx.x] = 0u;
}

// ---------------- kernel 1: x [B][C][N] f32 -> xT [B][N][C] bf16 ----------------
__global__ __launch_bounds__(256) void k_transpose(const float* __restrict__ x,
                                                   unsigned short* __restrict__ xT) {
  __shared__ float tile[64][65];
  const int b = blockIdx.z, c0 = blockIdx.y * 64, n0 = blockIdx.x * 64;
  const int t = threadIdx.x;
  {
    const int nl = t & 63, cl0 = t >> 6;
    const float* xp = x + ((size_t)b * CC + c0) * NN + n0;
#pragma unroll
    for (int r = 0; r < 16; r++) {
      const int cl = cl0 + r * 4;
      tile[cl][nl] = xp[(size_t)cl * NN + nl];
    }
  }
  __syncthreads();
  {
    const int cl = t & 63, nl0 = t >> 6;
    unsigned short* xtp = xT + ((size_t)b * NN + n0) * CC + c0;
#pragma unroll
    for (int r = 0; r < 16; r++) {
      const int nl = nl0 + r * 4;
      xtp[(size_t)nl * CC + cl] = f2bf(tile[cl][nl]);
    }
  }
}

// ------------- kernel 2: exact fp32 Q/K projection -> fp16; also max||k||^2 -------------
__global__ __launch_bounds__(256) void k_qkproj(
    const float* __restrict__ x, const float* __restrict__ wq, const float* __restrict__ bq,
    const float* __restrict__ wk, const float* __restrict__ bk,
    unsigned short* __restrict__ qf, unsigned short* __restrict__ kf) {
  __shared__ float xs[64][68];
  __shared__ float wqs[64][65];
  __shared__ float wks[64][65];
  const int b = blockIdx.y, n0 = blockIdx.x * 64;
  const int t = threadIdx.x;
  const int m4 = (t & 15) * 4, n4 = (t >> 4) * 4;
  const int cl = t & 63, r0 = t >> 6;
  float qa[4][4] = {}, ka[4][4] = {};
  for (int c0 = 0; c0 < CC; c0 += 64) {
    __syncthreads();
#pragma unroll
    for (int r = 0; r < 16; r++) {
      const int row = r0 + r * 4;
      xs[row][cl] = x[((size_t)b * CC + c0 + row) * NN + n0 + cl];
      wqs[row][cl] = wq[(size_t)row * CC + c0 + cl];
      wks[row][cl] = wk[(size_t)row * CC + c0 + cl];
    }
    __syncthreads();
#pragma unroll 8
    for (int cc = 0; cc < 64; cc++) {
      const f32x4 xv = *reinterpret_cast<const f32x4*>(&xs[cc][n4]);
#pragma unroll
      for (int mi = 0; mi < 4; mi++) {
        const float wqv = wqs[m4 + mi][cc];
        const float wkv = wks[m4 + mi][cc];
#pragma unroll
        for (int ni = 0; ni < 4; ni++) {
          qa[mi][ni] += wqv * xv[ni];
          ka[mi][ni] += wkv * xv[ni];
        }
      }
    }
  }
  float kss[4] = {0.f, 0.f, 0.f, 0.f};
#pragma unroll
  for (int ni = 0; ni < 4; ni++) {
    const int n = n0 + n4 + ni;
    const size_t base = ((size_t)b * NN + n) * MM + m4;
    unsigned short qh[4], kh[4];
#pragma unroll
    for (int mi = 0; mi < 4; mi++) {
      const float qv = qa[mi][ni] + bq[m4 + mi];
      const float kv = ka[mi][ni] + bk[m4 + mi];
      qh[mi] = f2h(qv);
      kh[mi] = f2h(kv);
      kss[ni] += kv * kv;
    }
    *reinterpret_cast<ushort4*>(qf + base) = make_ushort4(qh[0], qh[1], qh[2], qh[3]);
    *reinterpret_cast<ushort4*>(kf + base) = make_ushort4(kh[0], kh[1], kh[2], kh[3]);
  }
#pragma unroll
  for (int ni = 0; ni < 4; ni++) {
    kss[ni] += __shfl_xor(kss[ni], 1);
    kss[ni] += __shfl_xor(kss[ni], 2);
    kss[ni] += __shfl_xor(kss[ni], 4);
    kss[ni] += __shfl_xor(kss[ni], 8);
  }
  if ((t & 15) == 0) {
    float mx = fmaxf(fmaxf(kss[0], kss[1]), fmaxf(kss[2], kss[3]));
    atomicMax(&g_kmax[b], __float_as_uint(mx));
  }
}

// ---------------- kernel 3: V projection (bf16 MFMA) -> v [B][C][N] bf16 ----------------
__global__ __launch_bounds__(256) void k_vproj(
    const unsigned short* __restrict__ xT, const float* __restrict__ wv,
    const float* __restrict__ bv, unsigned short* __restrict__ vbf) {
  const int b = blockIdx.z, c0 = blockIdx.y * 64, n0 = blockIdx.x * 128;
  const int t = threadIdx.x, w = t >> 6, l = t & 63, lr = l & 15, g = l >> 4;
  const int nbase = n0 + w * 32;
  f32x4 acc[4][2] = {};
  for (int ks = 0; ks < 16; ks++) {
    const int kk = ks * 32 + g * 8;
    bf16x8 bfr[2];
#pragma unroll
    for (int nf = 0; nf < 2; nf++) {
      const int n = nbase + nf * 16 + lr;
      bfr[nf] = *reinterpret_cast<const bf16x8*>(xT + ((size_t)b * NN + n) * CC + kk);
    }
#pragma unroll
    for (int cf = 0; cf < 4; cf++) {
      const int c = c0 + cf * 16 + lr;
      const float* wp = wv + (size_t)c * CC + kk;
      const f32x4 w0 = *reinterpret_cast<const f32x4*>(wp);
      const f32x4 w1 = *reinterpret_cast<const f32x4*>(wp + 4);
      bf16x8 af;
      af[0] = (short)f2bf(w0[0]); af[1] = (short)f2bf(w0[1]);
      af[2] = (short)f2bf(w0[2]); af[3] = (short)f2bf(w0[3]);
      af[4] = (short)f2bf(w1[0]); af[5] = (short)f2bf(w1[1]);
      af[6] = (short)f2bf(w1[2]); af[7] = (short)f2bf(w1[3]);
      acc[cf][0] = __builtin_amdgcn_mfma_f32_16x16x32_bf16(af, bfr[0], acc[cf][0], 0, 0, 0);
      acc[cf][1] = __builtin_amdgcn_mfma_f32_16x16x32_bf16(af, bfr[1], acc[cf][1], 0, 0, 0);
    }
  }
#pragma unroll
  for (int cf = 0; cf < 4; cf++) {
#pragma unroll
    for (int r = 0; r < 4; r++) {
      const int c = c0 + cf * 16 + g * 4 + r;
      const float bvv = bv[c];
#pragma unroll
      for (int nf = 0; nf < 2; nf++) {
        const int n = nbase + nf * 16 + lr;
        vbf[((size_t)b * CC + c) * NN + n] = f2bf(acc[cf][nf][r] + bvv);
      }
    }
  }
}

// ---------------- kernel 4: attention + residual (bound-softmax) ----------------
// 8 waves (512 thr), I_TILE=64, JT=64, 64 iters, ONE raw barrier/iter
// (lgkmcnt drain only — global prefetches stay in flight across it).
// QK fp16 (A=K, B=Q): wave w computes S^T frags (if_=w&3, jf=(w>>2)*2+{0,1}),
// exp(s - mhat_i) from regs -> bf16 -> dbuf P_lds. PV: wave w owns c-strip
// [64w, 64w+64); V tile (8 frags) prefetched a full iter ahead; K prefetched
// mid-iter; setprio around PV MFMA cluster.
__global__ __launch_bounds__(512, 2) void k_attn(
    const unsigned short* __restrict__ qf, const unsigned short* __restrict__ kf,
    const unsigned short* __restrict__ vbf, const float* __restrict__ x,
    const float* __restrict__ gamma, float* __restrict__ out) {
  __shared__ unsigned short P_lds[2][64][74];  // [buf][i][j] bf16, 148B rows (5*lr bank rot)
  __shared__ float l_red[8][16];
  const int b = blockIdx.x & 7;  // batch-pinned XCD swizzle (512 blocks = 8*64)
  const int i0 = (blockIdx.x >> 3) * 64;
  const int t = threadIdx.x, w = t >> 6, l = t & 63, lr = l & 15, g = l >> 4;
  const int if_ = w & 3;         // QK i-frag owned by this wave
  const int jf0 = (w >> 2) * 2;  // QK j-frag pair base (0 or 2)
  const int wc = w * 64;         // PV channel strip

  // ---- Q fragments fp16 (only our i-frag), i = i0 + if_*16 + lr
  f16x8 qF[2];
  {
    const int i = i0 + if_ * 16 + lr;
#pragma unroll
    for (int ks = 0; ks < 2; ks++)
      qF[ks] = *reinterpret_cast<const f16x8*>(qf + ((size_t)b * NN + i) * MM + ks * 32 + g * 8);
  }
  // ---- mhat = ||q_i||*max||k||*(1+eps) - 44 (Cauchy-Schwarz bound)
  float mhat;
  {
    float ssq = 0.f;
#pragma unroll
    for (int ks = 0; ks < 2; ks++)
#pragma unroll
      for (int e = 0; e < 8; e++) {
        const float qv = (float)qF[ks][e];
        ssq += qv * qv;
      }
    ssq += __shfl_xor(ssq, 16);
    ssq += __shfl_xor(ssq, 32);
    mhat = sqrtf(ssq) * sqrtf(__uint_as_float(g_kmax[b])) * 1.001f - 44.f;
  }

  // K base: j = jb + (jf0+jj)*16 + lr
  const unsigned short* kp = kf + ((size_t)b * NN + jf0 * 16 + lr) * MM + g * 8;
  // V base: c = wc + cf*16 + lr, col j = jb + ks*32 + g*8
  const unsigned short* pv = vbf + ((size_t)b * CC + wc + lr) * NN + g * 8;

  f32x4 acc[4][4];  // [cf][if]
#pragma unroll
  for (int cf = 0; cf < 4; cf++)
#pragma unroll
    for (int i2 = 0; i2 < 4; i2++) acc[cf][i2] = f32x4{0.f, 0.f, 0.f, 0.f};
  float lsum = 0.f;

  // ---- prologue prefetch: K(0), V(0)
  f16x8 kF[2][2];  // [jj][ks]
#pragma unroll
  for (int jj = 0; jj < 2; jj++)
#pragma unroll
    for (int ks = 0; ks < 2; ks++)
      kF[jj][ks] = *reinterpret_cast<const f16x8*>(kp + (size_t)(jj * 16) * MM + ks * 32);
  bf16x8 vr[2][4];  // [ks][cf]
#pragma unroll
  for (int ks = 0; ks < 2; ks++)
#pragma unroll
    for (int cf = 0; cf < 4; cf++)
      vr[ks][cf] = *reinterpret_cast<const bf16x8*>(pv + (size_t)cf * (16 * NN) + ks * 32);

  for (int jb = 0; jb < NN; jb += 64) {
    const int buf = (jb >> 6) & 1;
    const int jn = (jb + 64) & (NN - 1);  // next tile (wrap harmless)

    // ---- QK (prefetched K) -> exp -> P write
#pragma unroll
    for (int jj = 0; jj < 2; jj++) {
      f32x4 sa = f32x4{0.f, 0.f, 0.f, 0.f};
      sa = __builtin_amdgcn_mfma_f32_16x16x32_f16(kF[jj][0], qF[0], sa, 0, 0, 0);
      sa = __builtin_amdgcn_mfma_f32_16x16x32_f16(kF[jj][1], qF[1], sa, 0, 0, 0);
      const float p0 = __expf(sa[0] - mhat), p1 = __expf(sa[1] - mhat);
      const float p2 = __expf(sa[2] - mhat), p3 = __expf(sa[3] - mhat);
      lsum += (p0 + p1) + (p2 + p3);
      ushort4 pq = make_ushort4(f2bf(p0), f2bf(p1), f2bf(p2), f2bf(p3));
      *reinterpret_cast<ushort4*>(&P_lds[buf][if_ * 16 + lr][(jf0 + jj) * 16 + g * 4]) = pq;
    }
    // ---- K prefetch for next tile (in flight across barrier; window = PV)
#pragma unroll
    for (int jj = 0; jj < 2; jj++)
#pragma unroll
      for (int ks = 0; ks < 2; ks++)
        kF[jj][ks] = *reinterpret_cast<const f16x8*>(kp + (size_t)(jn + jj * 16) * MM + ks * 32);

    // ---- raw barrier: drain LDS only; keep global prefetches in flight
    __builtin_amdgcn_sched_barrier(0);
    asm volatile("s_waitcnt lgkmcnt(0)" ::: "memory");
    __builtin_amdgcn_s_barrier();
    __builtin_amdgcn_sched_barrier(0);

    // ---- PV (V from regs, P from LDS)
    __builtin_amdgcn_s_setprio(1);
#pragma unroll
    for (int ks = 0; ks < 2; ks++) {
      bf16x8 pf[4];
#pragma unroll
      for (int i2 = 0; i2 < 4; i2++)
        pf[i2] = *reinterpret_cast<const bf16x8*>(&P_lds[buf][i2 * 16 + lr][ks * 32 + g * 8]);
#pragma unroll
      for (int cf = 0; cf < 4; cf++)
#pragma unroll
        for (int i2 = 0; i2 < 4; i2++)
          acc[cf][i2] = __builtin_amdgcn_mfma_f32_16x16x32_bf16(vr[ks][cf], pf[i2], acc[cf][i2], 0, 0, 0);
    }
    __builtin_amdgcn_s_setprio(0);

    // ---- V prefetch for next tile (in flight across next QK + barrier)
#pragma unroll
    for (int ks = 0; ks < 2; ks++)
#pragma unroll
      for (int cf = 0; cf < 4; cf++)
        vr[ks][cf] = *reinterpret_cast<const bf16x8*>(pv + (size_t)cf * (16 * NN) + jn + ks * 32);
  }

  // ---- final l reduction: over g (shfl), then across waves via LDS
  lsum += __shfl_xor(lsum, 16);
  lsum += __shfl_xor(lsum, 32);
  __syncthreads();
  if (l < 16) l_red[w][lr] = lsum;
  __syncthreads();
  const float gm = gamma[0];
  float inv[4];
#pragma unroll
  for (int i2 = 0; i2 < 4; i2++) inv[i2] = gm / (l_red[i2][lr] + l_red[i2 + 4][lr]);

  // ---- epilogue: out = gamma * O / l + x
#pragma unroll
  for (int cf = 0; cf < 4; cf++) {
#pragma unroll
    for (int r = 0; r < 4; r++) {
      const int c = wc + cf * 16 + g * 4 + r;
      const size_t rowo = ((size_t)b * CC + c) * NN;
#pragma unroll
      for (int i2 = 0; i2 < 4; i2++) {
        const int i = i0 + i2 * 16 + lr;
        out[rowo + i] = acc[cf][i2][r] * inv[i2] + x[rowo + i];
      }
    }
  }
}

extern "C" void kernel_launch(void* const* d_in, const int* in_sizes, int n_in,
                              void* d_out, int out_size, void* d_ws, size_t ws_size,
                              hipStream_t stream) {
  const float* x = (const float*)d_in[0];
  const float* wq = (const float*)d_in[1];
  const float* bq = (const float*)d_in[2];
  const float* wk = (const float*)d_in[3];
  const float* bk = (const float*)d_in[4];
  const float* wv = (const float*)d_in[5];
  const float* bv = (const float*)d_in[6];
  const float* gamma = (const float*)d_in[7];
  float* out = (float*)d_out;

  char* ws = (char*)d_ws;
  unsigned short* xT = (unsigned short*)(ws);              // 32 MB  [B][N][C] bf16
  unsigned short* vbf = (unsigned short*)(ws + 33554432);  // 32 MB  [B][C][N] bf16
  unsigned short* qfp = (unsigned short*)(ws + 67108864);  // 4 MB   [B][N][64] fp16
  unsigned short* kfp = (unsigned short*)(ws + 71303168);  // 4 MB   [B][N][64] fp16

  k_init<<<1, 64, 0, stream>>>();
  k_transpose<<<dim3(64, 8, 8), 256, 0, stream>>>(x, xT);
  k_qkproj<<<dim3(64, 8), 256, 0, stream>>>(x, wq, bq, wk, bk, qfp, kfp);
  k_vproj<<<dim3(32, 8, 8), 256, 0, stream>>>(xT, wv, bv, vbf);
  k_attn<<<dim3(512), 512, 0, stream>>>(qfp, kfp, vbf, x, gamma, out);
}

// Round 6
// 392.278 us; speedup vs baseline: 2.6677x; 1.5552x over previous
//
#include <hip/hip_runtime.h>
#include <hip/hip_bf16.h>

// PAM (position attention): B=8, C=512, mid=64, N=64*64=4096.
// Round 6:
//  - k_attn: I_TILE=128 with c-split (block = 128i x 256c) -> V re-read
//    traffic halved; XOR-swizzled P_lds [128][64] bf16 (canonical G4 shape);
//    V dbuf'd across 2-unrolled loop, prefetch right after barrier;
//    lgkm-only barrier (round-5 win) kept.
//  - k_qkproj: rewritten as 2-term (w hi/lo bf16) MFMA on xT -> 34 GF moves
//    from fp32 VALU (~200us) to matrix pipe (~20us). Outputs fp16 q/k.
//  - bound-softmax (Cauchy-Schwarz mhat) unchanged.

#define BB 8
#define CC 512
#define MM 64
#define NN 4096

typedef __attribute__((ext_vector_type(8))) short bf16x8;
typedef __attribute__((ext_vector_type(8))) _Float16 f16x8;
typedef __attribute__((ext_vector_type(4))) float f32x4;

__device__ unsigned g_kmax[BB];  // per-batch max ||k||^2 (uint-ordered f32)

__device__ __forceinline__ unsigned short f2bf(float f) {
  union { float f; unsigned u; } v; v.f = f;
  unsigned r = v.u + 0x7fffu + ((v.u >> 16) & 1u);  // RNE
  return (unsigned short)(r >> 16);
}
__device__ __forceinline__ float bf2f(unsigned short h) {
  union { unsigned u; float f; } v; v.u = ((unsigned)h) << 16;
  return v.f;
}
__device__ __forceinline__ unsigned short f2h(float f) {
  union { _Float16 h; unsigned short u; } v; v.h = (_Float16)f;
  return v.u;
}

__global__ void k_init() {
  if (threadIdx.x < BB) g_kmax[threadIdx.x] = 0u;
}

// ---------------- kernel 1: x [B][C][N] f32 -> xT [B][N][C] bf16 ----------------
__global__ __launch_bounds__(256) void k_transpose(const float* __restrict__ x,
                                                   unsigned short* __restrict__ xT) {
  __shared__ float tile[64][65];
  const int b = blockIdx.z, c0 = blockIdx.y * 64, n0 = blockIdx.x * 64;
  const int t = threadIdx.x;
  {
    const int nl = t & 63, cl0 = t >> 6;
    const float* xp = x + ((size_t)b * CC + c0) * NN + n0;
#pragma unroll
    for (int r = 0; r < 16; r++) {
      const int cl = cl0 + r * 4;
      tile[cl][nl] = xp[(size_t)cl * NN + nl];
    }
  }
  __syncthreads();
  {
    const int cl = t & 63, nl0 = t >> 6;
    unsigned short* xtp = xT + ((size_t)b * NN + n0) * CC + c0;
#pragma unroll
    for (int r = 0; r < 16; r++) {
      const int nl = nl0 + r * 4;
      xtp[(size_t)nl * CC + cl] = f2bf(tile[cl][nl]);
    }
  }
}

// ------------- kernel 2: Q/K projection via 2-term hi/lo bf16 MFMA -------------
// q[b][n][m] = sum_c wq[m][c] xT[b][n][c] + bq[m], stored fp16. Also g_kmax.
// Block: 256 thr / 4 waves; wave w owns m-frag w (16 m); n-tile = 128.
__global__ __launch_bounds__(256, 2) void k_qkproj(
    const unsigned short* __restrict__ xT,
    const float* __restrict__ wq, const float* __restrict__ bq,
    const float* __restrict__ wk, const float* __restrict__ bk,
    unsigned short* __restrict__ qf, unsigned short* __restrict__ kf) {
  __shared__ float ksl[4][8][16];
  const int b = blockIdx.x & 7;
  const int n0 = (blockIdx.x >> 3) * 128;
  const int t = threadIdx.x, w = t >> 6, l = t & 63, lr = l & 15, g = l >> 4;

  const float* wqp = wq + (size_t)(w * 16 + lr) * CC + g * 8;  // A row m = w*16+lr
  const float* wkp = wk + (size_t)(w * 16 + lr) * CC + g * 8;
  const unsigned short* xp = xT + ((size_t)b * NN + n0 + lr) * CC + g * 8;

  f32x4 qacc[8], kacc[8];
#pragma unroll
  for (int nf = 0; nf < 8; nf++) {
    qacc[nf] = f32x4{0.f, 0.f, 0.f, 0.f};
    kacc[nf] = f32x4{0.f, 0.f, 0.f, 0.f};
  }

  for (int cc = 0; cc < CC; cc += 32) {
    // w fragments, hi/lo split
    bf16x8 qhi8, qlo8, khi8, klo8;
    {
      const f32x4 a0 = *reinterpret_cast<const f32x4*>(wqp + cc);
      const f32x4 a1 = *reinterpret_cast<const f32x4*>(wqp + cc + 4);
      const f32x4 c0 = *reinterpret_cast<const f32x4*>(wkp + cc);
      const f32x4 c1 = *reinterpret_cast<const f32x4*>(wkp + cc + 4);
#pragma unroll
      for (int e = 0; e < 4; e++) {
        unsigned short h;
        h = f2bf(a0[e]); qhi8[e] = (short)h; qlo8[e] = (short)f2bf(a0[e] - bf2f(h));
        h = f2bf(a1[e]); qhi8[e + 4] = (short)h; qlo8[e + 4] = (short)f2bf(a1[e] - bf2f(h));
        h = f2bf(c0[e]); khi8[e] = (short)h; klo8[e] = (short)f2bf(c0[e] - bf2f(h));
        h = f2bf(c1[e]); khi8[e + 4] = (short)h; klo8[e + 4] = (short)f2bf(c1[e] - bf2f(h));
      }
    }
    bf16x8 xb[8];
#pragma unroll
    for (int nf = 0; nf < 8; nf++)
      xb[nf] = *reinterpret_cast<const bf16x8*>(xp + (size_t)nf * 16 * CC + cc);
#pragma unroll
    for (int nf = 0; nf < 8; nf++) {
      qacc[nf] = __builtin_amdgcn_mfma_f32_16x16x32_bf16(qhi8, xb[nf], qacc[nf], 0, 0, 0);
      qacc[nf] = __builtin_amdgcn_mfma_f32_16x16x32_bf16(qlo8, xb[nf], qacc[nf], 0, 0, 0);
      kacc[nf] = __builtin_amdgcn_mfma_f32_16x16x32_bf16(khi8, xb[nf], kacc[nf], 0, 0, 0);
      kacc[nf] = __builtin_amdgcn_mfma_f32_16x16x32_bf16(klo8, xb[nf], kacc[nf], 0, 0, 0);
    }
  }

  // epilogue: bias, fp16 store, ||k||^2
  float bqv[4], bkv[4];
#pragma unroll
  for (int r = 0; r < 4; r++) {
    bqv[r] = bq[w * 16 + g * 4 + r];
    bkv[r] = bk[w * 16 + g * 4 + r];
  }
  float kssp[8];
#pragma unroll
  for (int nf = 0; nf < 8; nf++) {
    float ks2 = 0.f;
    unsigned short qh[4], kh[4];
#pragma unroll
    for (int r = 0; r < 4; r++) {
      const float qv = qacc[nf][r] + bqv[r];
      const float kv = kacc[nf][r] + bkv[r];
      qh[r] = f2h(qv); kh[r] = f2h(kv);
      ks2 += kv * kv;
    }
    kssp[nf] = ks2;
    const int n = n0 + nf * 16 + lr;
    const size_t base = ((size_t)b * NN + n) * MM + w * 16 + g * 4;
    *reinterpret_cast<ushort4*>(qf + base) = make_ushort4(qh[0], qh[1], qh[2], qh[3]);
    *reinterpret_cast<ushort4*>(kf + base) = make_ushort4(kh[0], kh[1], kh[2], kh[3]);
  }
#pragma unroll
  for (int nf = 0; nf < 8; nf++) {
    kssp[nf] += __shfl_xor(kssp[nf], 16);
    kssp[nf] += __shfl_xor(kssp[nf], 32);
  }
  if (l < 16) {
#pragma unroll
    for (int nf = 0; nf < 8; nf++) ksl[w][nf][lr] = kssp[nf];
  }
  __syncthreads();
  if (t < 128) {
    const int nf = (t & 63) >> 4 | ((t >> 6) << 2);  // spread 8 nf over 2 waves
    const int lr2 = t & 15;
    float kn2 = ksl[0][nf][lr2] + ksl[1][nf][lr2] + ksl[2][nf][lr2] + ksl[3][nf][lr2];
#pragma unroll
    for (int d = 1; d < 64; d <<= 1) kn2 = fmaxf(kn2, __shfl_xor(kn2, d));
    if ((t & 63) == 0) atomicMax(&g_kmax[b], __float_as_uint(kn2));
  }
}

// ---------------- kernel 3: V projection (bf16 MFMA) -> v [B][C][N] bf16 ----------------
__global__ __launch_bounds__(256) void k_vproj(
    const unsigned short* __restrict__ xT, const float* __restrict__ wv,
    const float* __restrict__ bv, unsigned short* __restrict__ vbf) {
  const int b = blockIdx.z, c0 = blockIdx.y * 64, n0 = blockIdx.x * 128;
  const int t = threadIdx.x, w = t >> 6, l = t & 63, lr = l & 15, g = l >> 4;
  const int nbase = n0 + w * 32;
  f32x4 acc[4][2] = {};
  for (int ks = 0; ks < 16; ks++) {
    const int kk = ks * 32 + g * 8;
    bf16x8 bfr[2];
#pragma unroll
    for (int nf = 0; nf < 2; nf++) {
      const int n = nbase + nf * 16 + lr;
      bfr[nf] = *reinterpret_cast<const bf16x8*>(xT + ((size_t)b * NN + n) * CC + kk);
    }
#pragma unroll
    for (int cf = 0; cf < 4; cf++) {
      const int c = c0 + cf * 16 + lr;
      const float* wp = wv + (size_t)c * CC + kk;
      const f32x4 w0 = *reinterpret_cast<const f32x4*>(wp);
      const f32x4 w1 = *reinterpret_cast<const f32x4*>(wp + 4);
      bf16x8 af;
      af[0] = (short)f2bf(w0[0]); af[1] = (short)f2bf(w0[1]);
      af[2] = (short)f2bf(w0[2]); af[3] = (short)f2bf(w0[3]);
      af[4] = (short)f2bf(w1[0]); af[5] = (short)f2bf(w1[1]);
      af[6] = (short)f2bf(w1[2]); af[7] = (short)f2bf(w1[3]);
      acc[cf][0] = __builtin_amdgcn_mfma_f32_16x16x32_bf16(af, bfr[0], acc[cf][0], 0, 0, 0);
      acc[cf][1] = __builtin_amdgcn_mfma_f32_16x16x32_bf16(af, bfr[1], acc[cf][1], 0, 0, 0);
    }
  }
#pragma unroll
  for (int cf = 0; cf < 4; cf++) {
#pragma unroll
    for (int r = 0; r < 4; r++) {
      const int c = c0 + cf * 16 + g * 4 + r;
      const float bvv = bv[c];
#pragma unroll
      for (int nf = 0; nf < 2; nf++) {
        const int n = nbase + nf * 16 + lr;
        vbf[((size_t)b * CC + c) * NN + n] = f2bf(acc[cf][nf][r] + bvv);
      }
    }
  }
}

// ---------------- kernel 4: attention + residual (bound-softmax) ----------------
// 8 waves (512 thr); block = 128 i x 256 c (c-split over 2 blocks); JT=64.
// QK fp16 swapped (A=K,B=Q): wave w -> j-frag (w&3), i-frags (w>>2)*4+{0..3}.
// exp(s-mhat_i) from regs -> bf16 -> XOR-swizzled dbuf P_lds[2][128][64].
// PV: wave w owns 32-c strip; V dbuf'd in regs across 2-unrolled loop,
// prefetch issued right after the (lgkm-only) barrier. setprio on PV.
__global__ __launch_bounds__(512, 2) void k_attn(
    const unsigned short* __restrict__ qf, const unsigned short* __restrict__ kf,
    const unsigned short* __restrict__ vbf, const float* __restrict__ x,
    const float* __restrict__ gamma, float* __restrict__ out) {
  __shared__ unsigned short P_lds[2][128][64];
  __shared__ float l_red[8][4][16];
  const int b = blockIdx.x & 7;        // batch-pinned XCD swizzle
  const int idx = blockIdx.x >> 3;     // 0..63
  const int i0 = (idx >> 1) * 128;     // 32 i-tiles
  const int ch = idx & 1;              // c half
  const int t = threadIdx.x, w = t >> 6, l = t & 63, lr = l & 15, g = l >> 4;
  const int jf = w & 3, ig = w >> 2;
  const int wc = ch * 256 + w * 32;    // PV channel strip base

  // ---- Q fragments fp16: 4 i-frags a = ig*4+q, i = i0 + a*16 + lr
  f16x8 qF[4][2];
#pragma unroll
  for (int q = 0; q < 4; q++) {
    const int i = i0 + (ig * 4 + q) * 16 + lr;
#pragma unroll
    for (int ks = 0; ks < 2; ks++)
      qF[q][ks] = *reinterpret_cast<const f16x8*>(qf + ((size_t)b * NN + i) * MM + ks * 32 + g * 8);
  }
  // ---- mhat[q] = ||q_i|| * max||k|| * (1+eps) - 44
  float mhat[4];
  {
    const float kroot = sqrtf(__uint_as_float(g_kmax[b])) * 1.001f;
#pragma unroll
    for (int q = 0; q < 4; q++) {
      float ssq = 0.f;
#pragma unroll
      for (int ks = 0; ks < 2; ks++)
#pragma unroll
        for (int e = 0; e < 8; e++) {
          const float qv = (float)qF[q][ks][e];
          ssq += qv * qv;
        }
      ssq += __shfl_xor(ssq, 16);
      ssq += __shfl_xor(ssq, 32);
      mhat[q] = sqrtf(ssq) * kroot - 44.f;
    }
  }

  const unsigned short* kp = kf + ((size_t)b * NN + jf * 16 + lr) * MM + g * 8;
  const unsigned short* pv = vbf + ((size_t)b * CC + wc + lr) * NN + g * 8;

  f32x4 acc[2][8];
#pragma unroll
  for (int cf = 0; cf < 2; cf++)
#pragma unroll
    for (int i2 = 0; i2 < 8; i2++) acc[cf][i2] = f32x4{0.f, 0.f, 0.f, 0.f};
  float lsum[4] = {0.f, 0.f, 0.f, 0.f};

  // prologue prefetch: K(0), V(0)
  f16x8 kF[2];
#pragma unroll
  for (int ks = 0; ks < 2; ks++)
    kF[ks] = *reinterpret_cast<const f16x8*>(kp + ks * 32);
  bf16x8 vr0[2][2], vr1[2][2];
#pragma unroll
  for (int ks = 0; ks < 2; ks++)
#pragma unroll
    for (int cf = 0; cf < 2; cf++)
      vr0[ks][cf] = *reinterpret_cast<const bf16x8*>(pv + (size_t)cf * (16 * NN) + ks * 32);

  unsigned short* const pbase = &P_lds[0][0][0];

  auto iter = [&](int jb, bf16x8 (&vcur)[2][2], bf16x8 (&vnext)[2][2]) {
    const int buf = (jb >> 6) & 1;
    const int jn = (jb + 64) & (NN - 1);
    unsigned short* pb = pbase + buf * (128 * 64);

    // ---- QK (prefetched K) -> exp -> swizzled P write
    f32x4 sa[4];
#pragma unroll
    for (int q = 0; q < 4; q++) {
      sa[q] = __builtin_amdgcn_mfma_f32_16x16x32_f16(kF[0], qF[q][0],
                                                     f32x4{0.f, 0.f, 0.f, 0.f}, 0, 0, 0);
      sa[q] = __builtin_amdgcn_mfma_f32_16x16x32_f16(kF[1], qF[q][1], sa[q], 0, 0, 0);
    }
    // K prefetch for next tile (window: exp + barrier + PV)
#pragma unroll
    for (int ks = 0; ks < 2; ks++)
      kF[ks] = *reinterpret_cast<const f16x8*>(kp + (size_t)jn * MM + ks * 32);
#pragma unroll
    for (int q = 0; q < 4; q++) {
      const float p0 = __expf(sa[q][0] - mhat[q]);
      const float p1 = __expf(sa[q][1] - mhat[q]);
      const float p2 = __expf(sa[q][2] - mhat[q]);
      const float p3 = __expf(sa[q][3] - mhat[q]);
      lsum[q] += (p0 + p1) + (p2 + p3);
      const int row = (ig * 4 + q) * 16 + lr;
      const int colb = jf * 32 + g * 8;
      *reinterpret_cast<ushort4*>(
          (char*)pb + (row << 7) + (colb ^ ((row & 7) << 4))) =
          make_ushort4(f2bf(p0), f2bf(p1), f2bf(p2), f2bf(p3));
    }

    // ---- raw barrier: drain LDS only; global prefetches stay in flight
    __builtin_amdgcn_sched_barrier(0);
    asm volatile("s_waitcnt lgkmcnt(0)" ::: "memory");
    __builtin_amdgcn_s_barrier();
    __builtin_amdgcn_sched_barrier(0);

    // ---- V prefetch for NEXT tile (window: whole PV below)
#pragma unroll
    for (int ks = 0; ks < 2; ks++)
#pragma unroll
      for (int cf = 0; cf < 2; cf++)
        vnext[ks][cf] = *reinterpret_cast<const bf16x8*>(
            pv + (size_t)cf * (16 * NN) + jn + ks * 32);

    // ---- PV (V regs, P from swizzled LDS)
    __builtin_amdgcn_s_setprio(1);
#pragma unroll
    for (int ks = 0; ks < 2; ks++) {
#pragma unroll
      for (int i2 = 0; i2 < 8; i2++) {
        const int row = i2 * 16 + lr;
        const int colb = ks * 64 + g * 16;
        const bf16x8 pf = *reinterpret_cast<const bf16x8*>(
            (char*)pb + (row << 7) + (colb ^ ((row & 7) << 4)));
        acc[0][i2] = __builtin_amdgcn_mfma_f32_16x16x32_bf16(vcur[ks][0], pf, acc[0][i2], 0, 0, 0);
        acc[1][i2] = __builtin_amdgcn_mfma_f32_16x16x32_bf16(vcur[ks][1], pf, acc[1][i2], 0, 0, 0);
      }
    }
    __builtin_amdgcn_s_setprio(0);
  };

  for (int jb = 0; jb < NN; jb += 128) {
    iter(jb, vr0, vr1);
    iter(jb + 64, vr1, vr0);
  }

  // ---- l reduction: over g (shfl), then across j-frag waves via LDS
#pragma unroll
  for (int q = 0; q < 4; q++) {
    lsum[q] += __shfl_xor(lsum[q], 16);
    lsum[q] += __shfl_xor(lsum[q], 32);
  }
  __syncthreads();
  if (l < 16) {
#pragma unroll
    for (int q = 0; q < 4; q++) l_red[w][q][lr] = lsum[q];
  }
  __syncthreads();
  const float gm = gamma[0];
  float inv[8];
#pragma unroll
  for (int i2 = 0; i2 < 8; i2++) {
    const int ig2 = i2 >> 2, q = i2 & 3;
    inv[i2] = gm / (l_red[ig2 * 4 + 0][q][lr] + l_red[ig2 * 4 + 1][q][lr] +
                    l_red[ig2 * 4 + 2][q][lr] + l_red[ig2 * 4 + 3][q][lr]);
  }

  // ---- epilogue: out = gamma * O / l + x
#pragma unroll
  for (int cf = 0; cf < 2; cf++) {
#pragma unroll
    for (int r = 0; r < 4; r++) {
      const int c = wc + cf * 16 + g * 4 + r;
      const size_t rowo = ((size_t)b * CC + c) * NN;
#pragma unroll
      for (int i2 = 0; i2 < 8; i2++) {
        const int i = i0 + i2 * 16 + lr;
        out[rowo + i] = acc[cf][i2][r] * inv[i2] + x[rowo + i];
      }
    }
  }
}

extern "C" void kernel_launch(void* const* d_in, const int* in_sizes, int n_in,
                              void* d_out, int out_size, void* d_ws, size_t ws_size,
                              hipStream_t stream) {
  const float* x = (const float*)d_in[0];
  const float* wq = (const float*)d_in[1];
  const float* bq = (const float*)d_in[2];
  const float* wk = (const float*)d_in[3];
  const float* bk = (const float*)d_in[4];
  const float* wv = (const float*)d_in[5];
  const float* bv = (const float*)d_in[6];
  const float* gamma = (const float*)d_in[7];
  float* out = (float*)d_out;

  char* ws = (char*)d_ws;
  unsigned short* xT = (unsigned short*)(ws);              // 32 MB  [B][N][C] bf16
  unsigned short* vbf = (unsigned short*)(ws + 33554432);  // 32 MB  [B][C][N] bf16
  unsigned short* qfp = (unsigned short*)(ws + 67108864);  // 4 MB   [B][N][64] fp16
  unsigned short* kfp = (unsigned short*)(ws + 71303168);  // 4 MB   [B][N][64] fp16

  k_init<<<1, 64, 0, stream>>>();
  k_transpose<<<dim3(64, 8, 8), 256, 0, stream>>>(x, xT);
  k_qkproj<<<dim3(256), 256, 0, stream>>>(xT, wq, bq, wk, bk, qfp, kfp);
  k_vproj<<<dim3(32, 8, 8), 256, 0, stream>>>(xT, wv, bv, vbf);
  k_attn<<<dim3(512), 512, 0, stream>>>(qfp, kfp, vbf, x, gamma, out);
}

// Round 7
// 335.631 us; speedup vs baseline: 3.1179x; 1.1688x over previous
//
#include <hip/hip_runtime.h>
#include <hip/hip_bf16.h>

// PAM (position attention): B=8, C=512, mid=64, N=64*64=4096.
// Round 7:
//  - k_attn: single-region software pipeline — each barrier region contains
//    {V prefetch(t+1), QK MFMA(t+1), K prefetch(t+2), exp2+pack+store P(t+1),
//    PV(t)} so MFMA/VALU/LDS/VMEM overlap instead of lockstep phases.
//    exp2-direct (q pre-scaled by log2e) + v_cvt_pk_bf16_f32 P-pack.
//  - aux: k_wconv pre-converts weights to bf16 once; qkproj+vproj fused into
//    one 2560-block launch; qkproj n-tile 64 (2 blocks/CU).
//  - bound-softmax (Cauchy-Schwarz mhat, now in log2 units) unchanged.

#define BB 8
#define CC 512
#define MM 64
#define NN 4096
#define LOG2E 1.4426950408889634f

typedef __attribute__((ext_vector_type(8))) short bf16x8;
typedef __attribute__((ext_vector_type(8))) _Float16 f16x8;
typedef __attribute__((ext_vector_type(4))) float f32x4;

__device__ unsigned g_kmax[BB];  // per-batch max ||k||^2 (uint-ordered f32)

__device__ __forceinline__ unsigned short f2bf(float f) {
  union { float f; unsigned u; } v; v.f = f;
  unsigned r = v.u + 0x7fffu + ((v.u >> 16) & 1u);  // RNE
  return (unsigned short)(r >> 16);
}
__device__ __forceinline__ float bf2f(unsigned short h) {
  union { unsigned u; float f; } v; v.u = ((unsigned)h) << 16;
  return v.f;
}
__device__ __forceinline__ unsigned short f2h(float f) {
  union { _Float16 h; unsigned short u; } v; v.h = (_Float16)f;
  return v.u;
}

// ------------- kernel 0: weight pre-conversion + g_kmax init -------------
__global__ __launch_bounds__(256) void k_wconv(
    const float* __restrict__ wq, const float* __restrict__ wk,
    const float* __restrict__ wv,
    unsigned short* __restrict__ wqhi, unsigned short* __restrict__ wqlo,
    unsigned short* __restrict__ wkhi, unsigned short* __restrict__ wklo,
    unsigned short* __restrict__ wvbf) {
  const int tid = blockIdx.x * 256 + threadIdx.x;
  if (tid < BB) g_kmax[tid] = 0u;
  if (tid < MM * CC) {
    float v = wq[tid];
    unsigned short h = f2bf(v);
    wqhi[tid] = h; wqlo[tid] = f2bf(v - bf2f(h));
    v = wk[tid]; h = f2bf(v);
    wkhi[tid] = h; wklo[tid] = f2bf(v - bf2f(h));
  }
  for (int i = tid; i < CC * CC; i += 65536) wvbf[i] = f2bf(wv[i]);
}

// ---------------- kernel 1: x [B][C][N] f32 -> xT [B][N][C] bf16 ----------------
__global__ __launch_bounds__(256) void k_transpose(const float* __restrict__ x,
                                                   unsigned short* __restrict__ xT) {
  __shared__ float tile[64][65];
  const int b = blockIdx.z, c0 = blockIdx.y * 64, n0 = blockIdx.x * 64;
  const int t = threadIdx.x;
  {
    const int nl = t & 63, cl0 = t >> 6;
    const float* xp = x + ((size_t)b * CC + c0) * NN + n0;
#pragma unroll
    for (int r = 0; r < 16; r++) {
      const int cl = cl0 + r * 4;
      tile[cl][nl] = xp[(size_t)cl * NN + nl];
    }
  }
  __syncthreads();
  {
    const int cl = t & 63, nl0 = t >> 6;
    unsigned short* xtp = xT + ((size_t)b * NN + n0) * CC + c0;
#pragma unroll
    for (int r = 0; r < 16; r++) {
      const int nl = nl0 + r * 4;
      xtp[(size_t)nl * CC + cl] = f2bf(tile[cl][nl]);
    }
  }
}

// ------------- kernel 2 (fused): Q/K projection (blocks 0..511) +
//                                 V projection (blocks 512..2559) -------------
__global__ __launch_bounds__(256, 2) void k_proj(
    const unsigned short* __restrict__ xT,
    const unsigned short* __restrict__ wqhi, const unsigned short* __restrict__ wqlo,
    const unsigned short* __restrict__ wkhi, const unsigned short* __restrict__ wklo,
    const float* __restrict__ bq, const float* __restrict__ bk,
    const unsigned short* __restrict__ wvbf, const float* __restrict__ bv,
    unsigned short* __restrict__ qf, unsigned short* __restrict__ kf,
    unsigned short* __restrict__ vbf) {
  __shared__ float ksl[4][4][16];
  const int t = threadIdx.x, w = t >> 6, l = t & 63, lr = l & 15, g = l >> 4;

  if (blockIdx.x < 512) {
    // ---- Q/K projection: 2-term hi/lo bf16 MFMA; q pre-scaled by log2e
    const int b = blockIdx.x & 7;
    const int n0 = (blockIdx.x >> 3) * 64;
    const unsigned short* qhp = wqhi + (size_t)(w * 16 + lr) * CC + g * 8;
    const unsigned short* qlp = wqlo + (size_t)(w * 16 + lr) * CC + g * 8;
    const unsigned short* khp = wkhi + (size_t)(w * 16 + lr) * CC + g * 8;
    const unsigned short* klp = wklo + (size_t)(w * 16 + lr) * CC + g * 8;
    const unsigned short* xp = xT + ((size_t)b * NN + n0 + lr) * CC + g * 8;
    f32x4 qacc[4], kacc[4];
#pragma unroll
    for (int nf = 0; nf < 4; nf++) {
      qacc[nf] = f32x4{0.f, 0.f, 0.f, 0.f};
      kacc[nf] = f32x4{0.f, 0.f, 0.f, 0.f};
    }
    for (int cc = 0; cc < CC; cc += 32) {
      const bf16x8 qh8 = *reinterpret_cast<const bf16x8*>(qhp + cc);
      const bf16x8 ql8 = *reinterpret_cast<const bf16x8*>(qlp + cc);
      const bf16x8 kh8 = *reinterpret_cast<const bf16x8*>(khp + cc);
      const bf16x8 kl8 = *reinterpret_cast<const bf16x8*>(klp + cc);
      bf16x8 xb[4];
#pragma unroll
      for (int nf = 0; nf < 4; nf++)
        xb[nf] = *reinterpret_cast<const bf16x8*>(xp + (size_t)nf * 16 * CC + cc);
#pragma unroll
      for (int nf = 0; nf < 4; nf++) {
        qacc[nf] = __builtin_amdgcn_mfma_f32_16x16x32_bf16(qh8, xb[nf], qacc[nf], 0, 0, 0);
        qacc[nf] = __builtin_amdgcn_mfma_f32_16x16x32_bf16(ql8, xb[nf], qacc[nf], 0, 0, 0);
        kacc[nf] = __builtin_amdgcn_mfma_f32_16x16x32_bf16(kh8, xb[nf], kacc[nf], 0, 0, 0);
        kacc[nf] = __builtin_amdgcn_mfma_f32_16x16x32_bf16(kl8, xb[nf], kacc[nf], 0, 0, 0);
      }
    }
    float bqv[4], bkv[4];
#pragma unroll
    for (int r = 0; r < 4; r++) {
      bqv[r] = bq[w * 16 + g * 4 + r];
      bkv[r] = bk[w * 16 + g * 4 + r];
    }
    float kssp[4];
#pragma unroll
    for (int nf = 0; nf < 4; nf++) {
      float ks2 = 0.f;
      unsigned short qh[4], kh[4];
#pragma unroll
      for (int r = 0; r < 4; r++) {
        const float qv = (qacc[nf][r] + bqv[r]) * LOG2E;
        const float kv = kacc[nf][r] + bkv[r];
        qh[r] = f2h(qv); kh[r] = f2h(kv);
        ks2 += kv * kv;
      }
      kssp[nf] = ks2;
      const int n = n0 + nf * 16 + lr;
      const size_t base = ((size_t)b * NN + n) * MM + w * 16 + g * 4;
      *reinterpret_cast<ushort4*>(qf + base) = make_ushort4(qh[0], qh[1], qh[2], qh[3]);
      *reinterpret_cast<ushort4*>(kf + base) = make_ushort4(kh[0], kh[1], kh[2], kh[3]);
    }
#pragma unroll
    for (int nf = 0; nf < 4; nf++) {
      kssp[nf] += __shfl_xor(kssp[nf], 16);
      kssp[nf] += __shfl_xor(kssp[nf], 32);
    }
    if (l < 16) {
#pragma unroll
      for (int nf = 0; nf < 4; nf++) ksl[w][nf][lr] = kssp[nf];
    }
    __syncthreads();
    if (t < 64) {
      const int nf2 = t >> 4, lr2 = t & 15;
      float kn2 = ksl[0][nf2][lr2] + ksl[1][nf2][lr2] + ksl[2][nf2][lr2] + ksl[3][nf2][lr2];
#pragma unroll
      for (int d = 1; d < 64; d <<= 1) kn2 = fmaxf(kn2, __shfl_xor(kn2, d));
      if (t == 0) atomicMax(&g_kmax[b], __float_as_uint(kn2));
    }
  } else {
    // ---- V projection (bf16 MFMA, pre-converted wv)
    const int blk = blockIdx.x - 512;
    const int b = blk >> 8, c0 = ((blk >> 5) & 7) * 64, n0 = (blk & 31) * 128;
    const int nbase = n0 + w * 32;
    f32x4 acc[4][2];
#pragma unroll
    for (int cf = 0; cf < 4; cf++) {
      acc[cf][0] = f32x4{0.f, 0.f, 0.f, 0.f};
      acc[cf][1] = f32x4{0.f, 0.f, 0.f, 0.f};
    }
    for (int ks = 0; ks < 16; ks++) {
      const int kk = ks * 32 + g * 8;
      bf16x8 bfr[2];
#pragma unroll
      for (int nf = 0; nf < 2; nf++) {
        const int n = nbase + nf * 16 + lr;
        bfr[nf] = *reinterpret_cast<const bf16x8*>(xT + ((size_t)b * NN + n) * CC + kk);
      }
#pragma unroll
      for (int cf = 0; cf < 4; cf++) {
        const bf16x8 af = *reinterpret_cast<const bf16x8*>(
            wvbf + (size_t)(c0 + cf * 16 + lr) * CC + kk);
        acc[cf][0] = __builtin_amdgcn_mfma_f32_16x16x32_bf16(af, bfr[0], acc[cf][0], 0, 0, 0);
        acc[cf][1] = __builtin_amdgcn_mfma_f32_16x16x32_bf16(af, bfr[1], acc[cf][1], 0, 0, 0);
      }
    }
#pragma unroll
    for (int cf = 0; cf < 4; cf++) {
#pragma unroll
      for (int r = 0; r < 4; r++) {
        const int c = c0 + cf * 16 + g * 4 + r;
        const float bvv = bv[c];
#pragma unroll
        for (int nf = 0; nf < 2; nf++) {
          const int n = nbase + nf * 16 + lr;
          vbf[((size_t)b * CC + c) * NN + n] = f2bf(acc[cf][nf][r] + bvv);
        }
      }
    }
  }
}

// ---------------- kernel 3: attention + residual (bound-softmax) ----------------
// 8 waves (512 thr); block = 128 i x 256 c; JT=64; 64 regions, 1 barrier each.
// Region t: {V prefetch(t+1), QK(t+1) fp16 MFMA, K prefetch(t+2),
//            exp2+cvt_pk+store P(t+1)->buf^1, PV(t) from buf} -> barrier.
__global__ __launch_bounds__(512, 2) void k_attn(
    const unsigned short* __restrict__ qf, const unsigned short* __restrict__ kf,
    const unsigned short* __restrict__ vbf, const float* __restrict__ x,
    const float* __restrict__ gamma, float* __restrict__ out) {
  __shared__ unsigned short P_lds[2][128][64];  // 16 KB per buffer, XOR-swizzled
  __shared__ float l_red[8][4][16];
  const int b = blockIdx.x & 7;      // batch-pinned XCD swizzle
  const int idx = blockIdx.x >> 3;   // 0..63
  const int i0 = (idx >> 1) * 128;
  const int ch = idx & 1;
  const int t = threadIdx.x, w = t >> 6, l = t & 63, lr = l & 15, g = l >> 4;
  const int jf = w & 3, ig = w >> 2;
  const int wc = ch * 256 + w * 32;

  // ---- Q fragments (fp16, pre-scaled by log2e)
  f16x8 qF[4][2];
#pragma unroll
  for (int q = 0; q < 4; q++) {
    const int i = i0 + (ig * 4 + q) * 16 + lr;
#pragma unroll
    for (int ks = 0; ks < 2; ks++)
      qF[q][ks] = *reinterpret_cast<const f16x8*>(qf + ((size_t)b * NN + i) * MM + ks * 32 + g * 8);
  }
  // ---- mhat[q] (log2 units): ||q~||*||k||max*(1+eps) - 44*log2e
  float mhat[4];
  {
    const float kroot = sqrtf(__uint_as_float(g_kmax[b])) * 1.001f;
#pragma unroll
    for (int q = 0; q < 4; q++) {
      float ssq = 0.f;
#pragma unroll
      for (int ks = 0; ks < 2; ks++)
#pragma unroll
        for (int e = 0; e < 8; e++) {
          const float qv = (float)qF[q][ks][e];
          ssq += qv * qv;
        }
      ssq += __shfl_xor(ssq, 16);
      ssq += __shfl_xor(ssq, 32);
      mhat[q] = sqrtf(ssq) * kroot - 63.4786f;
    }
  }

  const unsigned short* kp = kf + ((size_t)b * NN + jf * 16 + lr) * MM + g * 8;
  const unsigned short* pv = vbf + ((size_t)b * CC + wc + lr) * NN + g * 8;

  f32x4 acc[2][8];
#pragma unroll
  for (int cf = 0; cf < 2; cf++)
#pragma unroll
    for (int i2 = 0; i2 < 8; i2++) acc[cf][i2] = f32x4{0.f, 0.f, 0.f, 0.f};
  float lsum[4] = {0.f, 0.f, 0.f, 0.f};

  char* const pbase = (char*)&P_lds[0][0][0];
  int off_s[4];  // P store byte offsets (within one buffer)
#pragma unroll
  for (int q = 0; q < 4; q++) {
    const int row = (ig * 4 + q) * 16 + lr;
    off_s[q] = (row << 7) + ((jf * 32 + g * 8) ^ ((row & 7) << 4));
  }

  // ---- prologue: K(0), V(0); QK(0)->buf0; K(1)
  f16x8 kA[2], kB[2];
#pragma unroll
  for (int ks = 0; ks < 2; ks++)
    kA[ks] = *reinterpret_cast<const f16x8*>(kp + (size_t)ks * 32);
  bf16x8 va[2][2], vb[2][2];
#pragma unroll
  for (int ks = 0; ks < 2; ks++)
#pragma unroll
    for (int cf = 0; cf < 2; cf++)
      va[ks][cf] = *reinterpret_cast<const bf16x8*>(pv + (size_t)cf * (16 * NN) + ks * 32);
#pragma unroll
  for (int q = 0; q < 4; q++) {
    f32x4 sa = __builtin_amdgcn_mfma_f32_16x16x32_f16(kA[0], qF[q][0],
                                                      f32x4{0.f, 0.f, 0.f, 0.f}, 0, 0, 0);
    sa = __builtin_amdgcn_mfma_f32_16x16x32_f16(kA[1], qF[q][1], sa, 0, 0, 0);
    const float p0 = __builtin_amdgcn_exp2f(sa[0] - mhat[q]);
    const float p1 = __builtin_amdgcn_exp2f(sa[1] - mhat[q]);
    const float p2 = __builtin_amdgcn_exp2f(sa[2] - mhat[q]);
    const float p3 = __builtin_amdgcn_exp2f(sa[3] - mhat[q]);
    lsum[q] += (p0 + p1) + (p2 + p3);
    unsigned r01, r23;
    asm volatile("v_cvt_pk_bf16_f32 %0, %1, %2" : "=v"(r01) : "v"(p0), "v"(p1));
    asm volatile("v_cvt_pk_bf16_f32 %0, %1, %2" : "=v"(r23) : "v"(p2), "v"(p3));
    *reinterpret_cast<uint2*>(pbase + off_s[q]) = make_uint2(r01, r23);
  }
#pragma unroll
  for (int ks = 0; ks < 2; ks++)
    kB[ks] = *reinterpret_cast<const f16x8*>(kp + (size_t)64 * MM + ks * 32);
  __builtin_amdgcn_sched_barrier(0);
  asm volatile("s_waitcnt lgkmcnt(0)" ::: "memory");
  __builtin_amdgcn_s_barrier();
  __builtin_amdgcn_sched_barrier(0);

  // ---- main regions
  auto region = [&](int jb, bf16x8 (&vcur)[2][2], bf16x8 (&vnext)[2][2],
                    f16x8 (&kuse)[2], f16x8 (&kpre)[2]) {
    const int par = (jb >> 6) & 1;
    const int j1 = (jb + 64) & (NN - 1);
    const int j2 = (jb + 128) & (NN - 1);
    // V prefetch for next region (window: whole region)
#pragma unroll
    for (int ks = 0; ks < 2; ks++)
#pragma unroll
      for (int cf = 0; cf < 2; cf++)
        vnext[ks][cf] = *reinterpret_cast<const bf16x8*>(
            pv + (size_t)cf * (16 * NN) + j1 + ks * 32);
    // QK(t+1)
    f32x4 sa[4];
#pragma unroll
    for (int q = 0; q < 4; q++) {
      sa[q] = __builtin_amdgcn_mfma_f32_16x16x32_f16(kuse[0], qF[q][0],
                                                     f32x4{0.f, 0.f, 0.f, 0.f}, 0, 0, 0);
      sa[q] = __builtin_amdgcn_mfma_f32_16x16x32_f16(kuse[1], qF[q][1], sa[q], 0, 0, 0);
    }
    // K prefetch two tiles ahead (window: this region + next QK)
#pragma unroll
    for (int ks = 0; ks < 2; ks++)
      kpre[ks] = *reinterpret_cast<const f16x8*>(kp + (size_t)j2 * MM + ks * 32);
    // exp2 + pack + store P(t+1) into buf par^1
    const bool vld = (jb + 64) < NN;
    char* const pw = pbase + ((par ^ 1) << 14);
#pragma unroll
    for (int q = 0; q < 4; q++) {
      const float p0 = __builtin_amdgcn_exp2f(sa[q][0] - mhat[q]);
      const float p1 = __builtin_amdgcn_exp2f(sa[q][1] - mhat[q]);
      const float p2 = __builtin_amdgcn_exp2f(sa[q][2] - mhat[q]);
      const float p3 = __builtin_amdgcn_exp2f(sa[q][3] - mhat[q]);
      if (vld) lsum[q] += (p0 + p1) + (p2 + p3);
      unsigned r01, r23;
      asm volatile("v_cvt_pk_bf16_f32 %0, %1, %2" : "=v"(r01) : "v"(p0), "v"(p1));
      asm volatile("v_cvt_pk_bf16_f32 %0, %1, %2" : "=v"(r23) : "v"(p2), "v"(p3));
      *reinterpret_cast<uint2*>(pw + off_s[q]) = make_uint2(r01, r23);
    }
    // PV(t) from buf par
    char* const pr = pbase + (par << 14);
    __builtin_amdgcn_s_setprio(1);
#pragma unroll
    for (int ks = 0; ks < 2; ks++) {
#pragma unroll
      for (int i2 = 0; i2 < 8; i2++) {
        const int row = i2 * 16 + lr;
        const int colb = ks * 64 + g * 16;
        const bf16x8 pf = *reinterpret_cast<const bf16x8*>(
            pr + (row << 7) + (colb ^ ((row & 7) << 4)));
        acc[0][i2] = __builtin_amdgcn_mfma_f32_16x16x32_bf16(vcur[ks][0], pf, acc[0][i2], 0, 0, 0);
        acc[1][i2] = __builtin_amdgcn_mfma_f32_16x16x32_bf16(vcur[ks][1], pf, acc[1][i2], 0, 0, 0);
      }
    }
    __builtin_amdgcn_s_setprio(0);
    __builtin_amdgcn_sched_barrier(0);
    asm volatile("s_waitcnt lgkmcnt(0)" ::: "memory");
    __builtin_amdgcn_s_barrier();
    __builtin_amdgcn_sched_barrier(0);
  };

  for (int tt = 0; tt < 32; tt++) {
    region(tt * 128, va, vb, kB, kA);
    region(tt * 128 + 64, vb, va, kA, kB);
  }

  // ---- l reduction
#pragma unroll
  for (int q = 0; q < 4; q++) {
    lsum[q] += __shfl_xor(lsum[q], 16);
    lsum[q] += __shfl_xor(lsum[q], 32);
  }
  __syncthreads();
  if (l < 16) {
#pragma unroll
    for (int q = 0; q < 4; q++) l_red[w][q][lr] = lsum[q];
  }
  __syncthreads();
  const float gm = gamma[0];
  float inv[8];
#pragma unroll
  for (int i2 = 0; i2 < 8; i2++) {
    const int ig2 = i2 >> 2, q = i2 & 3;
    inv[i2] = gm / (l_red[ig2 * 4 + 0][q][lr] + l_red[ig2 * 4 + 1][q][lr] +
                    l_red[ig2 * 4 + 2][q][lr] + l_red[ig2 * 4 + 3][q][lr]);
  }

  // ---- epilogue: out = gamma * O / l + x
#pragma unroll
  for (int cf = 0; cf < 2; cf++) {
#pragma unroll
    for (int r = 0; r < 4; r++) {
      const int c = wc + cf * 16 + g * 4 + r;
      const size_t rowo = ((size_t)b * CC + c) * NN;
#pragma unroll
      for (int i2 = 0; i2 < 8; i2++) {
        const int i = i0 + i2 * 16 + lr;
        out[rowo + i] = acc[cf][i2][r] * inv[i2] + x[rowo + i];
      }
    }
  }
}

extern "C" void kernel_launch(void* const* d_in, const int* in_sizes, int n_in,
                              void* d_out, int out_size, void* d_ws, size_t ws_size,
                              hipStream_t stream) {
  const float* x = (const float*)d_in[0];
  const float* wq = (const float*)d_in[1];
  const float* bq = (const float*)d_in[2];
  const float* wk = (const float*)d_in[3];
  const float* bk = (const float*)d_in[4];
  const float* wv = (const float*)d_in[5];
  const float* bv = (const float*)d_in[6];
  const float* gamma = (const float*)d_in[7];
  float* out = (float*)d_out;

  char* ws = (char*)d_ws;
  unsigned short* xT = (unsigned short*)(ws);                 // 32 MB [B][N][C] bf16
  unsigned short* vbf = (unsigned short*)(ws + 33554432);     // 32 MB [B][C][N] bf16
  unsigned short* qfp = (unsigned short*)(ws + 67108864);     // 4 MB  [B][N][64] fp16 (log2e-scaled)
  unsigned short* kfp = (unsigned short*)(ws + 71303168);     // 4 MB  [B][N][64] fp16
  unsigned short* wqhi = (unsigned short*)(ws + 75497472);    // 64 KB
  unsigned short* wqlo = (unsigned short*)(ws + 75563008);    // 64 KB
  unsigned short* wkhi = (unsigned short*)(ws + 75628544);    // 64 KB
  unsigned short* wklo = (unsigned short*)(ws + 75694080);    // 64 KB
  unsigned short* wvbf = (unsigned short*)(ws + 75759616);    // 512 KB

  k_wconv<<<256, 256, 0, stream>>>(wq, wk, wv, wqhi, wqlo, wkhi, wklo, wvbf);
  k_transpose<<<dim3(64, 8, 8), 256, 0, stream>>>(x, xT);
  k_proj<<<2560, 256, 0, stream>>>(xT, wqhi, wqlo, wkhi, wklo, bq, bk, wvbf, bv,
                                   qfp, kfp, vbf);
  k_attn<<<dim3(512), 512, 0, stream>>>(qfp, kfp, vbf, x, gamma, out);
}